// Round 12
// baseline (299.485 us; speedup 1.0000x reference)
//
#include <hip/hip_runtime.h>
#include <hip/hip_bf16.h>
#include <math.h>

#define NH 20
#define HD 64
#define E_DIM 1280
#define T_TOK 8192
#define NSEQ 8
#define N4 (E_DIM * E_DIM / 4)

#define SCALE_LOG2 0.1803368801111204f   // 0.125 * log2(e)

typedef unsigned short u16;
typedef unsigned int u32;
typedef __attribute__((ext_vector_type(8))) short bf16x8;
typedef __attribute__((ext_vector_type(4))) float f32x4;
typedef __attribute__((ext_vector_type(16))) float f32x16;

__device__ __forceinline__ float bf2f(u16 h) {
  union { float f; unsigned u; } c; c.u = ((unsigned)h) << 16; return c.f;
}
__device__ __forceinline__ u16 f2bf(float f) {
  union { float f; unsigned u; } c; c.f = f;
  unsigned u = c.u;
  return (u16)((u + 0x7fffu + ((u >> 16) & 1u)) >> 16);
}
__device__ __forceinline__ u32 cvtpk(float lo, float hi) {
  u32 r;
  asm("v_cvt_pk_bf16_f32 %0, %1, %2" : "=v"(r) : "v"(lo), "v"(hi));
  return r;
}

__device__ __forceinline__ void gld_lds16(const void* g, void* l) {
  __builtin_amdgcn_global_load_lds((const __attribute__((address_space(1))) void*)g,
                                   (__attribute__((address_space(3))) void*)l,
                                   16, 0, 0);
}

#define BARR() __builtin_amdgcn_s_barrier()
#define VMC2() asm volatile("s_waitcnt vmcnt(2)" ::: "memory")
#define VMC4() asm volatile("s_waitcnt vmcnt(4)" ::: "memory")
#define VMC0() asm volatile("s_waitcnt vmcnt(0)" ::: "memory")

// -------- weights fp32 -> bf16 + RoPE table, one launch --------
// blocks [0, 6400): cvt 4*N4 float4s; blocks [6400, 6528): rope table.
#define CVT_BLOCKS 6400
__global__ __launch_bounds__(256) void prep_kernel(const float* __restrict__ Wq,
                                                   const float* __restrict__ Wk,
                                                   const float* __restrict__ Wv,
                                                   const float* __restrict__ Wo,
                                                   u16* __restrict__ wqkv,
                                                   u16* __restrict__ wo,
                                                   float2* __restrict__ tab) {
  if (blockIdx.x < CVT_BLOCKS) {
    int i = blockIdx.x * 256 + threadIdx.x;
    if (i >= 4 * N4) return;
    int r = i / N4;
    int l = i - r * N4;
    const float* src = (r == 0) ? Wq : (r == 1) ? Wk : (r == 2) ? Wv : Wo;
    float4 v = ((const float4*)src)[l];
    ushort4 ov;
    ov.x = f2bf(v.x); ov.y = f2bf(v.y); ov.z = f2bf(v.z); ov.w = f2bf(v.w);
    if (r < 3) ((ushort4*)wqkv)[(size_t)r * N4 + l] = ov;
    else       ((ushort4*)wo)[l] = ov;
  } else {
    int i = (blockIdx.x - CVT_BLOCKS) * 256 + threadIdx.x;   // 0..32767
    if (i >= 1024 * 32) return;
    int pos = i >> 5, dm = i & 31;
    float freq = exp2f(-(float)dm * (13.287712379549449f / 32.0f));
    float f = (float)pos * freq;
    tab[i] = make_float2(cosf(f), sinf(f));
  }
}

// ---------------- pre-norm: h = LN(x)*w + b, bf16 out ----------------
__global__ __launch_bounds__(320) void ln_x_kernel(const float* __restrict__ x,
                                                   const float* __restrict__ w,
                                                   const float* __restrict__ b,
                                                   u16* __restrict__ h) {
  const int row = blockIdx.x;
  const int tid = threadIdx.x;
  const float4 xv = ((const float4*)(x + (size_t)row * E_DIM))[tid];
  float s  = xv.x + xv.y + xv.z + xv.w;
  float s2 = xv.x*xv.x + xv.y*xv.y + xv.z*xv.z + xv.w*xv.w;
#pragma unroll
  for (int m = 1; m < 64; m <<= 1) { s += __shfl_xor(s, m); s2 += __shfl_xor(s2, m); }
  __shared__ float ss[5], ss2[5];
  if ((tid & 63) == 0) { ss[tid >> 6] = s; ss2[tid >> 6] = s2; }
  __syncthreads();
  s  = ss[0] + ss[1] + ss[2] + ss[3] + ss[4];
  s2 = ss2[0] + ss2[1] + ss2[2] + ss2[3] + ss2[4];
  const float mean = s * (1.0f / E_DIM);
  const float var  = s2 * (1.0f / E_DIM) - mean * mean;
  const float rstd = rsqrtf(var + 1e-5f);
  const float4 wv = ((const float4*)w)[tid];
  const float4 bv = ((const float4*)b)[tid];
  ushort4 o;
  o.x = f2bf((xv.x - mean) * rstd * wv.x + bv.x);
  o.y = f2bf((xv.y - mean) * rstd * wv.y + bv.y);
  o.z = f2bf((xv.z - mean) * rstd * wv.z + bv.z);
  o.w = f2bf((xv.w - mean) * rstd * wv.w + bv.w);
  ((ushort4*)(h + (size_t)row * E_DIM))[tid] = o;
}

// ------- fused LN (no bias) + RoPE for q and k in one launch -------------
__global__ __launch_bounds__(320) void ln_rope2_kernel(const u16* __restrict__ preq,
                                                       const u16* __restrict__ prek,
                                                       const float* __restrict__ wq,
                                                       const float* __restrict__ wk,
                                                       const int* __restrict__ cu,
                                                       const float2* __restrict__ tab,
                                                       u16* __restrict__ outq,
                                                       u16* __restrict__ outk) {
  const int sel = blockIdx.x >> 13;
  const int row = blockIdx.x & (T_TOK - 1);
  const u16* pre = sel ? prek : preq;
  const float* w = sel ? wk : wq;
  u16* outp = sel ? outk : outq;
  const float oscale = sel ? 1.0f : SCALE_LOG2;
  const int tid = threadIdx.x;
  __shared__ float y[E_DIM];
  const ushort4 qv = ((const ushort4*)(pre + (size_t)row * E_DIM))[tid];
  float v0 = bf2f(qv.x), v1 = bf2f(qv.y), v2 = bf2f(qv.z), v3 = bf2f(qv.w);
  float s  = v0 + v1 + v2 + v3;
  float s2 = v0*v0 + v1*v1 + v2*v2 + v3*v3;
#pragma unroll
  for (int m = 1; m < 64; m <<= 1) { s += __shfl_xor(s, m); s2 += __shfl_xor(s2, m); }
  __shared__ float ss[5], ss2[5];
  if ((tid & 63) == 0) { ss[tid >> 6] = s; ss2[tid >> 6] = s2; }
  __syncthreads();
  s  = ss[0] + ss[1] + ss[2] + ss[3] + ss[4];
  s2 = ss2[0] + ss2[1] + ss2[2] + ss2[3] + ss2[4];
  const float mean = s * (1.0f / E_DIM);
  const float var  = s2 * (1.0f / E_DIM) - mean * mean;
  const float rstd = rsqrtf(var + 1e-5f);
  const int e0 = tid * 4;
  float4 wv = ((const float4*)w)[tid];
  wv.x *= oscale; wv.y *= oscale; wv.z *= oscale; wv.w *= oscale;
  y[e0 + 0] = (v0 - mean) * rstd * wv.x;
  y[e0 + 1] = (v1 - mean) * rstd * wv.y;
  y[e0 + 2] = (v2 - mean) * rstd * wv.z;
  y[e0 + 3] = (v3 - mean) * rstd * wv.w;
  __syncthreads();
  int seg = 0;
#pragma unroll
  for (int bb = 1; bb < NSEQ + 1; bb++) if (cu[bb] <= row) seg = bb;
  const int pos = row - cu[seg];
  const int d0 = e0 & 63;
  const int hbase = e0 - d0;
  const float4* tp = (const float4*)(tab + pos * 32 + (d0 & 31));
  const float4 t0 = tp[0], t1 = tp[1];
  const float cs_[4] = {t0.x, t0.z, t1.x, t1.z};
  const float sn_[4] = {t0.y, t0.w, t1.y, t1.w};
  const bool lo = (d0 < 32);
  ushort4 o;
#pragma unroll
  for (int i = 0; i < 4; i++) {
    const int d = d0 + i;
    float r;
    if (lo) r = y[hbase + d] * cs_[i] - y[hbase + d + 32] * sn_[i];
    else    r = y[hbase + d] * cs_[i] + y[hbase + d - 32] * sn_[i];
    ((u16*)&o)[i] = f2bf(r);
  }
  ((ushort4*)(outp + (size_t)row * E_DIM))[tid] = o;
}

// ---------------- 256x256 8-phase GEMM (R9 schedule: best measured) -------
template <int MODE, int K>
__global__ __launch_bounds__(512) void gemm256(const u16* __restrict__ A,
                                               const u16* __restrict__ B,
                                               u16* __restrict__ preq,
                                               u16* __restrict__ prek,
                                               u16* __restrict__ vT,
                                               float* __restrict__ Cf) {
  __shared__ u16 As[2][16384];
  __shared__ u16 Bs[2][16384];
  const int tid = threadIdx.x;
  const int wid = tid >> 6, lane = tid & 63;
  const int l16 = lane & 15, lq = lane >> 4;
  const int wm = wid >> 2, wn = wid & 3;
  const int bm = blockIdx.x & 31;            // M = 8192 -> 32 tiles
  const int bn = blockIdx.x >> 5;
  const int m0 = bm << 8, n0 = bn << 8;
  const int sw = l16 & 7;

  const int row0 = tid >> 3;                 // 0..63
  const int ch0 = ((tid & 7) ^ (row0 & 7)) << 3;
  const u16* Abase = A + (size_t)(m0 + row0) * K + ch0;
  const u16* Bbase = B + (size_t)(n0 + row0) * K + ch0;
  const int dst0 = tid * 8;

  const int CA = (wm * 128 + l16) * 64;
  const int CB = (wn * 64 + l16) * 64;
  const int ch_0 = ((0 | lq) ^ sw) << 3;
  const int ch_1 = ((4 | lq) ^ sw) << 3;

  f32x4 acc[8][4] = {};
  bf16x8 aF[4][2], bF[2][2][2];

#define STG(Larr, bufp, hh, gbase, kt) do {                                     \
    const u16* g_ = (gbase) + (size_t)(hh) * 128 * K + (size_t)(kt) * 64;       \
    gld_lds16(g_, &Larr[bufp][(hh) * 8192 + dst0]);                             \
    gld_lds16(g_ + (size_t)64 * K, &Larr[bufp][(hh) * 8192 + dst0 + 4096]);     \
  } while (0)

#define RDA(bufp, a) do {                                                       \
    _Pragma("unroll") for (int mb = 0; mb < 4; mb++) {                          \
      aF[mb][0] = *(const bf16x8*)(&As[bufp][CA + (a) * 4096 + mb * 1024 + ch_0]); \
      aF[mb][1] = *(const bf16x8*)(&As[bufp][CA + (a) * 4096 + mb * 1024 + ch_1]); \
    } } while (0)

#define RDB(bufp, b) do {                                                       \
    _Pragma("unroll") for (int nb = 0; nb < 2; nb++) {                          \
      bF[b][nb][0] = *(const bf16x8*)(&Bs[bufp][CB + (b) * 2048 + nb * 1024 + ch_0]); \
      bF[b][nb][1] = *(const bf16x8*)(&Bs[bufp][CB + (b) * 2048 + nb * 1024 + ch_1]); \
    } } while (0)

#define MFQ(a, b) do {                                                          \
    __builtin_amdgcn_s_setprio(1);                                              \
    _Pragma("unroll") for (int mb = 0; mb < 4; mb++)                            \
    _Pragma("unroll") for (int nb = 0; nb < 2; nb++)                            \
    _Pragma("unroll") for (int kk = 0; kk < 2; kk++)                            \
      acc[(a) * 4 + mb][(b) * 2 + nb] = __builtin_amdgcn_mfma_f32_16x16x32_bf16( \
          aF[mb][kk], bF[b][nb][kk], acc[(a) * 4 + mb][(b) * 2 + nb], 0, 0, 0); \
    __builtin_amdgcn_s_setprio(0); } while (0)

  STG(Bs, 0, 0, Bbase, 0);
  STG(As, 0, 0, Abase, 0);
  STG(Bs, 0, 1, Bbase, 0);
  STG(As, 0, 1, Abase, 0);
  STG(Bs, 1, 0, Bbase, 1);
  STG(As, 1, 0, Abase, 1);
  VMC4();
  BARR();

  const int NIT = K / 128;
  for (int i = 0; i < NIT; i++) {
    const bool lastI = (i == NIT - 1);
    const int k1 = 2 * i + 1, k2 = 2 * i + 2, k3 = 2 * i + 3;
    // P1: compute K(2i) q(0,0); stage K(2i+1) Bh1
    RDA(0, 0); RDB(0, 0);
    STG(Bs, 1, 1, Bbase, k1);
    MFQ(0, 0); BARR();
    // P2: q(0,1); stage K(2i+1) Ah1
    RDB(0, 1);
    STG(As, 1, 1, Abase, k1);
    MFQ(0, 1); BARR();
    // P3: q(1,0); stage K(2i+2) Bh0; publish K(2i+1)
    RDA(0, 1);
    if (!lastI) STG(Bs, 0, 0, Bbase, k2);
    MFQ(1, 0);
    if (!lastI) VMC2(); else VMC0();
    BARR();
    // P4: q(1,1); stage K(2i+2) Ah0
    if (!lastI) STG(As, 0, 0, Abase, k2);
    MFQ(1, 1); BARR();
    // P5: compute K(2i+1) q(0,0); stage K(2i+2) Bh1
    RDA(1, 0); RDB(1, 0);
    if (!lastI) STG(Bs, 0, 1, Bbase, k2);
    MFQ(0, 0); BARR();
    // P6: q(0,1); stage K(2i+2) Ah1
    RDB(1, 1);
    if (!lastI) STG(As, 0, 1, Abase, k2);
    MFQ(0, 1); BARR();
    // P7: q(1,0); stage K(2i+3) Bh0; publish K(2i+2)
    RDA(1, 1);
    if (!lastI) STG(Bs, 1, 0, Bbase, k3);
    MFQ(1, 0);
    if (!lastI) VMC2();
    BARR();
    // P8: q(1,1); stage K(2i+3) Ah0
    if (!lastI) {
      STG(As, 1, 0, Abase, k3);
      MFQ(1, 1); BARR();
    } else {
      MFQ(1, 1);
    }
  }
#undef STG
#undef RDA
#undef RDB
#undef MFQ

  if (MODE == 0) {
    if (n0 < 2560) {
      u16* dst; int c0;
      if (n0 < 1280) { dst = preq; c0 = n0; }
      else           { dst = prek; c0 = n0 - 1280; }
#pragma unroll
      for (int mi = 0; mi < 8; mi++)
#pragma unroll
        for (int j = 0; j < 4; j++) {
          const size_t rowo = (size_t)(m0 + wm * 128 + mi * 16 + lq * 4 + j) * E_DIM;
#pragma unroll
          for (int ni = 0; ni < 4; ni++)
            dst[rowo + c0 + wn * 64 + ni * 16 + l16] = f2bf(acc[mi][ni][j]);
        }
    } else {
      const int c0 = n0 - 2560;
#pragma unroll
      for (int mi = 0; mi < 8; mi++)
#pragma unroll
        for (int ni = 0; ni < 4; ni++) {
          ushort4 pkt;
          pkt.x = f2bf(acc[mi][ni][0]); pkt.y = f2bf(acc[mi][ni][1]);
          pkt.z = f2bf(acc[mi][ni][2]); pkt.w = f2bf(acc[mi][ni][3]);
          const size_t off = (size_t)(c0 + wn * 64 + ni * 16 + l16) * T_TOK +
                             (m0 + wm * 128 + mi * 16 + lq * 4);
          *(ushort4*)(vT + off) = pkt;
        }
    }
  } else {
#pragma unroll
    for (int mi = 0; mi < 8; mi++)
#pragma unroll
      for (int j = 0; j < 4; j++) {
        const size_t rowo = (size_t)(m0 + wm * 128 + mi * 16 + lq * 4 + j) * E_DIM;
#pragma unroll
        for (int ni = 0; ni < 4; ni++)
          Cf[rowo + n0 + wn * 64 + ni * 16 + l16] = acc[mi][ni][j];
      }
  }
}

// ---------------- flash attention: swapped-QK 32x32, no-max exp2 softmax ----
// __launch_bounds__(256,5): cap VGPR at ~102 so 5 waves/SIMD (LDS allows 5
// blocks/CU; previously VGPR=104 capped at 4).
__global__ __launch_bounds__(256, 5) void attn_kernel(const u16* __restrict__ q,
                                                      const u16* __restrict__ k,
                                                      const u16* __restrict__ vT,
                                                      const int* __restrict__ cu,
                                                      u16* __restrict__ o) {
  const int bx = blockIdx.x;
  const int hb = bx % (NH * NSEQ);
  const int qt = bx / (NH * NSEQ);
  const int hh = hb % NH;
  const int b  = hb / NH;
  const int base = cu[b];
  const int nkt  = (cu[b + 1] - base) >> 6;
  const int tid  = threadIdx.x;
  const int wid  = tid >> 6, lane = tid & 63;
  const int l31  = lane & 31, hi = lane >> 5;

  __shared__ u16 Ks[2][64 * 64];
  __shared__ u16 Vs[2][64 * 64];

  const int qrow = base + qt * 128 + wid * 32 + l31;
  bf16x8 qf[4];
#pragma unroll
  for (int kk = 0; kk < 4; kk++)
    qf[kk] = *(const bf16x8*)(q + (size_t)qrow * E_DIM + hh * 64 + kk * 16 + hi * 8);

  f32x16 acc0 = {}, acc1 = {};
  float lrow = 0.f;

  const int r0 = tid >> 3;
  const int chs = tid & 7;
  const int cs0 = (chs ^ (r0 & 7)) << 3;
  const int r1 = r0 + 32;
  const int cs1 = (chs ^ (r1 & 7)) << 3;
  const u16* kg0 = k  + (size_t)(base + r0) * E_DIM + hh * 64 + cs0;
  const u16* kg1 = k  + (size_t)(base + r1) * E_DIM + hh * 64 + cs1;
  const u16* vg0 = vT + (size_t)(hh * 64 + r0) * T_TOK + base + cs0;
  const u16* vg1 = vT + (size_t)(hh * 64 + r1) * T_TOK + base + cs1;
  const int ldsoff = wid * 512;

  gld_lds16(kg0, &Ks[0][ldsoff]);
  gld_lds16(kg1, &Ks[0][2048 + ldsoff]);
  gld_lds16(vg0, &Vs[0][ldsoff]);
  gld_lds16(vg1, &Vs[0][2048 + ldsoff]);
  __syncthreads();

  int cur = 0;
  for (int kt = 0; kt < nkt; kt++) {
    if (kt + 1 < nkt) {
      const size_t ko = (size_t)(kt + 1) * 64 * E_DIM;
      const int vo = (kt + 1) * 64;
      u16* kd = Ks[cur ^ 1];
      u16* vd = Vs[cur ^ 1];
      gld_lds16(kg0 + ko, kd + ldsoff);
      gld_lds16(kg1 + ko, kd + 2048 + ldsoff);
      gld_lds16(vg0 + vo, vd + ldsoff);
      gld_lds16(vg1 + vo, vd + 2048 + ldsoff);
    }
    const u16* Kc = Ks[cur];
    const u16* Vc = Vs[cur];

    f32x16 S0 = {}, S1 = {};
#pragma unroll
    for (int kk = 0; kk < 4; kk++) {
      const int c0 = (((kk << 1) | hi) ^ (l31 & 7)) << 3;
      const bf16x8 kf0 = *(const bf16x8*)(Kc + l31 * 64 + c0);
      const bf16x8 kf1 = *(const bf16x8*)(Kc + (32 + l31) * 64 + c0);
      S0 = __builtin_amdgcn_mfma_f32_32x32x16_bf16(kf0, qf[kk], S0, 0, 0, 0);
      S1 = __builtin_amdgcn_mfma_f32_32x32x16_bf16(kf1, qf[kk], S1, 0, 0, 0);
    }

    float rs0 = 0.f, rs1 = 0.f, rs2 = 0.f, rs3 = 0.f;
#pragma unroll
    for (int r = 0; r < 16; r += 4) {
      S0[r + 0] = exp2f(S0[r + 0]); S0[r + 1] = exp2f(S0[r + 1]);
      S0[r + 2] = exp2f(S0[r + 2]); S0[r + 3] = exp2f(S0[r + 3]);
      rs0 += S0[r + 0]; rs1 += S0[r + 1]; rs2 += S0[r + 2]; rs3 += S0[r + 3];
    }
#pragma unroll
    for (int r = 0; r < 16; r += 4) {
      S1[r + 0] = exp2f(S1[r + 0]); S1[r + 1] = exp2f(S1[r + 1]);
      S1[r + 2] = exp2f(S1[r + 2]); S1[r + 3] = exp2f(S1[r + 3]);
      rs0 += S1[r + 0]; rs1 += S1[r + 1]; rs2 += S1[r + 2]; rs3 += S1[r + 3];
    }
    float rs = (rs0 + rs1) + (rs2 + rs3);
    rs += __shfl_xor(rs, 32);
    lrow += rs;

    u32 pw[4][4];
#pragma unroll
    for (int ks = 0; ks < 4; ks++) {
      const int g = (ks & 1) << 3;
      u32 A0, A1, B0, B1;
      if (ks < 2) {
        A0 = cvtpk(S0[g + 0], S0[g + 1]); A1 = cvtpk(S0[g + 2], S0[g + 3]);
        B0 = cvtpk(S0[g + 4], S0[g + 5]); B1 = cvtpk(S0[g + 6], S0[g + 7]);
      } else {
        A0 = cvtpk(S1[g + 0], S1[g + 1]); A1 = cvtpk(S1[g + 2], S1[g + 3]);
        B0 = cvtpk(S1[g + 4], S1[g + 5]); B1 = cvtpk(S1[g + 6], S1[g + 7]);
      }
      asm("v_permlane32_swap_b32 %0, %1" : "+v"(A0), "+v"(B0));
      asm("v_permlane32_swap_b32 %0, %1" : "+v"(A1), "+v"(B1));
      pw[ks][0] = A0; pw[ks][1] = A1; pw[ks][2] = B0; pw[ks][3] = B1;
    }

#pragma unroll
    for (int ks = 0; ks < 4; ks++) {
      const bf16x8 pa = *(const bf16x8*)&pw[ks][0];
      const int c0 = (((ks << 1) | hi) ^ (l31 & 7)) << 3;
      const bf16x8 vf0 = *(const bf16x8*)(Vc + l31 * 64 + c0);
      const bf16x8 vf1 = *(const bf16x8*)(Vc + (32 + l31) * 64 + c0);
      acc0 = __builtin_amdgcn_mfma_f32_32x32x16_bf16(pa, vf0, acc0, 0, 0, 0);
      acc1 = __builtin_amdgcn_mfma_f32_32x32x16_bf16(pa, vf1, acc1, 0, 0, 0);
    }
    __syncthreads();
    cur ^= 1;
  }

  const float linv = 1.0f / lrow;
  const int tok0 = base + qt * 128 + wid * 32;
#pragma unroll
  for (int r = 0; r < 16; r++) {
    const int qr = (r & 3) + 8 * (r >> 2) + 4 * hi;
    const float ls = __shfl(linv, qr);
    const size_t ro = (size_t)(tok0 + qr) * E_DIM + hh * 64 + l31;
    o[ro]      = f2bf(acc0[r] * ls);
    o[ro + 32] = f2bf(acc1[r] * ls);
  }
}

// ---------------- launch ----------------
extern "C" void kernel_launch(void* const* d_in, const int* in_sizes, int n_in,
                              void* d_out, int out_size, void* d_ws, size_t ws_size,
                              hipStream_t stream) {
  const float* x      = (const float*)d_in[0];
  const int*   cu     = (const int*)d_in[1];
  const float* norm_w = (const float*)d_in[3];
  const float* norm_b = (const float*)d_in[4];
  const float* Wq     = (const float*)d_in[5];
  const float* Wk     = (const float*)d_in[6];
  const float* Wv     = (const float*)d_in[7];
  const float* Wo     = (const float*)d_in[8];
  const float* lnq    = (const float*)d_in[9];
  const float* lnk    = (const float*)d_in[10];
  float* out = (float*)d_out;

  const size_t EE2 = (size_t)E_DIM * E_DIM * 2;
  const size_t TE2 = (size_t)T_TOK * E_DIM * 2;
  char* p = (char*)d_ws;
  u16* wqkv = (u16*)p; p += 3 * EE2;
  u16* wo_b = (u16*)p; p += EE2;
  u16* h_b  = (u16*)p; p += TE2;   // later: attention output
  u16* preq = (u16*)p; p += TE2;
  u16* prek = (u16*)p; p += TE2;
  u16* vT_b = (u16*)p; p += TE2;
  float2* tab = (float2*)p; p += 1024 * 32 * sizeof(float2);

  prep_kernel<<<CVT_BLOCKS + 128, 256, 0, stream>>>(Wq, Wk, Wv, Wo, wqkv, wo_b, tab);
  ln_x_kernel<<<T_TOK, 320, 0, stream>>>(x, norm_w, norm_b, h_b);

  // QKV: M=8192, N=3840 -> 32 x 15 = 480 blocks
  gemm256<0, E_DIM><<<480, 512, 0, stream>>>(h_b, wqkv, preq, prek, vT_b, nullptr);

  // fused q+k LN+RoPE (q pre-scaled by 0.125*log2e)
  ln_rope2_kernel<<<2 * T_TOK, 320, 0, stream>>>(preq, prek, lnq, lnk, cu, tab, preq, prek);

  attn_kernel<<<8 * NH * NSEQ, 256, 0, stream>>>(preq, prek, vT_b, cu, h_b);

  // OUT: M=8192, N=1280 -> 32 x 5 = 160 blocks
  gemm256<1, E_DIM><<<160, 512, 0, stream>>>(h_b, wo_b, nullptr, nullptr, nullptr, out);
}

// Round 13
// 252.296 us; speedup vs baseline: 1.1870x; 1.1870x over previous
//
#include <hip/hip_runtime.h>
#include <hip/hip_bf16.h>
#include <math.h>

#define NH 20
#define HD 64
#define E_DIM 1280
#define T_TOK 8192
#define NSEQ 8
#define N4 (E_DIM * E_DIM / 4)

#define SCALE_LOG2 0.1803368801111204f   // 0.125 * log2(e)

typedef unsigned short u16;
typedef unsigned int u32;
typedef __attribute__((ext_vector_type(8))) short bf16x8;
typedef __attribute__((ext_vector_type(4))) float f32x4;
typedef __attribute__((ext_vector_type(16))) float f32x16;

__device__ __forceinline__ float bf2f(u16 h) {
  union { float f; unsigned u; } c; c.u = ((unsigned)h) << 16; return c.f;
}
__device__ __forceinline__ u16 f2bf(float f) {
  union { float f; unsigned u; } c; c.f = f;
  unsigned u = c.u;
  return (u16)((u + 0x7fffu + ((u >> 16) & 1u)) >> 16);
}
__device__ __forceinline__ u32 cvtpk(float lo, float hi) {
  u32 r;
  asm("v_cvt_pk_bf16_f32 %0, %1, %2" : "=v"(r) : "v"(lo), "v"(hi));
  return r;
}

__device__ __forceinline__ void gld_lds16(const void* g, void* l) {
  __builtin_amdgcn_global_load_lds((const __attribute__((address_space(1))) void*)g,
                                   (__attribute__((address_space(3))) void*)l,
                                   16, 0, 0);
}

#define BARR() __builtin_amdgcn_s_barrier()
#define VMC2() asm volatile("s_waitcnt vmcnt(2)" ::: "memory")
#define VMC4() asm volatile("s_waitcnt vmcnt(4)" ::: "memory")
#define VMC0() asm volatile("s_waitcnt vmcnt(0)" ::: "memory")

// -------- weights fp32 -> bf16 + RoPE table, one launch --------
// blocks [0, 6400): cvt 4*N4 float4s; blocks [6400, 6528): rope table.
#define CVT_BLOCKS 6400
__global__ __launch_bounds__(256) void prep_kernel(const float* __restrict__ Wq,
                                                   const float* __restrict__ Wk,
                                                   const float* __restrict__ Wv,
                                                   const float* __restrict__ Wo,
                                                   u16* __restrict__ wqkv,
                                                   u16* __restrict__ wo,
                                                   float2* __restrict__ tab) {
  if (blockIdx.x < CVT_BLOCKS) {
    int i = blockIdx.x * 256 + threadIdx.x;
    if (i >= 4 * N4) return;
    int r = i / N4;
    int l = i - r * N4;
    const float* src = (r == 0) ? Wq : (r == 1) ? Wk : (r == 2) ? Wv : Wo;
    float4 v = ((const float4*)src)[l];
    ushort4 ov;
    ov.x = f2bf(v.x); ov.y = f2bf(v.y); ov.z = f2bf(v.z); ov.w = f2bf(v.w);
    if (r < 3) ((ushort4*)wqkv)[(size_t)r * N4 + l] = ov;
    else       ((ushort4*)wo)[l] = ov;
  } else {
    int i = (blockIdx.x - CVT_BLOCKS) * 256 + threadIdx.x;   // 0..32767
    if (i >= 1024 * 32) return;
    int pos = i >> 5, dm = i & 31;
    float freq = exp2f(-(float)dm * (13.287712379549449f / 32.0f));
    float f = (float)pos * freq;
    tab[i] = make_float2(cosf(f), sinf(f));
  }
}

// ---------------- pre-norm: h = LN(x)*w + b, bf16 out ----------------
__global__ __launch_bounds__(320) void ln_x_kernel(const float* __restrict__ x,
                                                   const float* __restrict__ w,
                                                   const float* __restrict__ b,
                                                   u16* __restrict__ h) {
  const int row = blockIdx.x;
  const int tid = threadIdx.x;
  const float4 xv = ((const float4*)(x + (size_t)row * E_DIM))[tid];
  float s  = xv.x + xv.y + xv.z + xv.w;
  float s2 = xv.x*xv.x + xv.y*xv.y + xv.z*xv.z + xv.w*xv.w;
#pragma unroll
  for (int m = 1; m < 64; m <<= 1) { s += __shfl_xor(s, m); s2 += __shfl_xor(s2, m); }
  __shared__ float ss[5], ss2[5];
  if ((tid & 63) == 0) { ss[tid >> 6] = s; ss2[tid >> 6] = s2; }
  __syncthreads();
  s  = ss[0] + ss[1] + ss[2] + ss[3] + ss[4];
  s2 = ss2[0] + ss2[1] + ss2[2] + ss2[3] + ss2[4];
  const float mean = s * (1.0f / E_DIM);
  const float var  = s2 * (1.0f / E_DIM) - mean * mean;
  const float rstd = rsqrtf(var + 1e-5f);
  const float4 wv = ((const float4*)w)[tid];
  const float4 bv = ((const float4*)b)[tid];
  ushort4 o;
  o.x = f2bf((xv.x - mean) * rstd * wv.x + bv.x);
  o.y = f2bf((xv.y - mean) * rstd * wv.y + bv.y);
  o.z = f2bf((xv.z - mean) * rstd * wv.z + bv.z);
  o.w = f2bf((xv.w - mean) * rstd * wv.w + bv.w);
  ((ushort4*)(h + (size_t)row * E_DIM))[tid] = o;
}

// ------- fused LN (no bias) + RoPE for q and k in one launch -------------
__global__ __launch_bounds__(320) void ln_rope2_kernel(const u16* __restrict__ preq,
                                                       const u16* __restrict__ prek,
                                                       const float* __restrict__ wq,
                                                       const float* __restrict__ wk,
                                                       const int* __restrict__ cu,
                                                       const float2* __restrict__ tab,
                                                       u16* __restrict__ outq,
                                                       u16* __restrict__ outk) {
  const int sel = blockIdx.x >> 13;
  const int row = blockIdx.x & (T_TOK - 1);
  const u16* pre = sel ? prek : preq;
  const float* w = sel ? wk : wq;
  u16* outp = sel ? outk : outq;
  const float oscale = sel ? 1.0f : SCALE_LOG2;
  const int tid = threadIdx.x;
  __shared__ float y[E_DIM];
  const ushort4 qv = ((const ushort4*)(pre + (size_t)row * E_DIM))[tid];
  float v0 = bf2f(qv.x), v1 = bf2f(qv.y), v2 = bf2f(qv.z), v3 = bf2f(qv.w);
  float s  = v0 + v1 + v2 + v3;
  float s2 = v0*v0 + v1*v1 + v2*v2 + v3*v3;
#pragma unroll
  for (int m = 1; m < 64; m <<= 1) { s += __shfl_xor(s, m); s2 += __shfl_xor(s2, m); }
  __shared__ float ss[5], ss2[5];
  if ((tid & 63) == 0) { ss[tid >> 6] = s; ss2[tid >> 6] = s2; }
  __syncthreads();
  s  = ss[0] + ss[1] + ss[2] + ss[3] + ss[4];
  s2 = ss2[0] + ss2[1] + ss2[2] + ss2[3] + ss2[4];
  const float mean = s * (1.0f / E_DIM);
  const float var  = s2 * (1.0f / E_DIM) - mean * mean;
  const float rstd = rsqrtf(var + 1e-5f);
  const int e0 = tid * 4;
  float4 wv = ((const float4*)w)[tid];
  wv.x *= oscale; wv.y *= oscale; wv.z *= oscale; wv.w *= oscale;
  y[e0 + 0] = (v0 - mean) * rstd * wv.x;
  y[e0 + 1] = (v1 - mean) * rstd * wv.y;
  y[e0 + 2] = (v2 - mean) * rstd * wv.z;
  y[e0 + 3] = (v3 - mean) * rstd * wv.w;
  __syncthreads();
  int seg = 0;
#pragma unroll
  for (int bb = 1; bb < NSEQ + 1; bb++) if (cu[bb] <= row) seg = bb;
  const int pos = row - cu[seg];
  const int d0 = e0 & 63;
  const int hbase = e0 - d0;
  const float4* tp = (const float4*)(tab + pos * 32 + (d0 & 31));
  const float4 t0 = tp[0], t1 = tp[1];
  const float cs_[4] = {t0.x, t0.z, t1.x, t1.z};
  const float sn_[4] = {t0.y, t0.w, t1.y, t1.w};
  const bool lo = (d0 < 32);
  ushort4 o;
#pragma unroll
  for (int i = 0; i < 4; i++) {
    const int d = d0 + i;
    float r;
    if (lo) r = y[hbase + d] * cs_[i] - y[hbase + d + 32] * sn_[i];
    else    r = y[hbase + d] * cs_[i] + y[hbase + d - 32] * sn_[i];
    ((u16*)&o)[i] = f2bf(r);
  }
  ((ushort4*)(outp + (size_t)row * E_DIM))[tid] = o;
}

// ---------------- 256x256 8-phase GEMM (R9 schedule: best measured) -------
template <int MODE, int K>
__global__ __launch_bounds__(512) void gemm256(const u16* __restrict__ A,
                                               const u16* __restrict__ B,
                                               u16* __restrict__ preq,
                                               u16* __restrict__ prek,
                                               u16* __restrict__ vT,
                                               float* __restrict__ Cf) {
  __shared__ u16 As[2][16384];
  __shared__ u16 Bs[2][16384];
  const int tid = threadIdx.x;
  const int wid = tid >> 6, lane = tid & 63;
  const int l16 = lane & 15, lq = lane >> 4;
  const int wm = wid >> 2, wn = wid & 3;
  const int bm = blockIdx.x & 31;            // M = 8192 -> 32 tiles
  const int bn = blockIdx.x >> 5;
  const int m0 = bm << 8, n0 = bn << 8;
  const int sw = l16 & 7;

  const int row0 = tid >> 3;                 // 0..63
  const int ch0 = ((tid & 7) ^ (row0 & 7)) << 3;
  const u16* Abase = A + (size_t)(m0 + row0) * K + ch0;
  const u16* Bbase = B + (size_t)(n0 + row0) * K + ch0;
  const int dst0 = tid * 8;

  const int CA = (wm * 128 + l16) * 64;
  const int CB = (wn * 64 + l16) * 64;
  const int ch_0 = ((0 | lq) ^ sw) << 3;
  const int ch_1 = ((4 | lq) ^ sw) << 3;

  f32x4 acc[8][4] = {};
  bf16x8 aF[4][2], bF[2][2][2];

#define STG(Larr, bufp, hh, gbase, kt) do {                                     \
    const u16* g_ = (gbase) + (size_t)(hh) * 128 * K + (size_t)(kt) * 64;       \
    gld_lds16(g_, &Larr[bufp][(hh) * 8192 + dst0]);                             \
    gld_lds16(g_ + (size_t)64 * K, &Larr[bufp][(hh) * 8192 + dst0 + 4096]);     \
  } while (0)

#define RDA(bufp, a) do {                                                       \
    _Pragma("unroll") for (int mb = 0; mb < 4; mb++) {                          \
      aF[mb][0] = *(const bf16x8*)(&As[bufp][CA + (a) * 4096 + mb * 1024 + ch_0]); \
      aF[mb][1] = *(const bf16x8*)(&As[bufp][CA + (a) * 4096 + mb * 1024 + ch_1]); \
    } } while (0)

#define RDB(bufp, b) do {                                                       \
    _Pragma("unroll") for (int nb = 0; nb < 2; nb++) {                          \
      bF[b][nb][0] = *(const bf16x8*)(&Bs[bufp][CB + (b) * 2048 + nb * 1024 + ch_0]); \
      bF[b][nb][1] = *(const bf16x8*)(&Bs[bufp][CB + (b) * 2048 + nb * 1024 + ch_1]); \
    } } while (0)

#define MFQ(a, b) do {                                                          \
    __builtin_amdgcn_s_setprio(1);                                              \
    _Pragma("unroll") for (int mb = 0; mb < 4; mb++)                            \
    _Pragma("unroll") for (int nb = 0; nb < 2; nb++)                            \
    _Pragma("unroll") for (int kk = 0; kk < 2; kk++)                            \
      acc[(a) * 4 + mb][(b) * 2 + nb] = __builtin_amdgcn_mfma_f32_16x16x32_bf16( \
          aF[mb][kk], bF[b][nb][kk], acc[(a) * 4 + mb][(b) * 2 + nb], 0, 0, 0); \
    __builtin_amdgcn_s_setprio(0); } while (0)

  STG(Bs, 0, 0, Bbase, 0);
  STG(As, 0, 0, Abase, 0);
  STG(Bs, 0, 1, Bbase, 0);
  STG(As, 0, 1, Abase, 0);
  STG(Bs, 1, 0, Bbase, 1);
  STG(As, 1, 0, Abase, 1);
  VMC4();
  BARR();

  const int NIT = K / 128;
  for (int i = 0; i < NIT; i++) {
    const bool lastI = (i == NIT - 1);
    const int k1 = 2 * i + 1, k2 = 2 * i + 2, k3 = 2 * i + 3;
    // P1: compute K(2i) q(0,0); stage K(2i+1) Bh1
    RDA(0, 0); RDB(0, 0);
    STG(Bs, 1, 1, Bbase, k1);
    MFQ(0, 0); BARR();
    // P2: q(0,1); stage K(2i+1) Ah1
    RDB(0, 1);
    STG(As, 1, 1, Abase, k1);
    MFQ(0, 1); BARR();
    // P3: q(1,0); stage K(2i+2) Bh0; publish K(2i+1)
    RDA(0, 1);
    if (!lastI) STG(Bs, 0, 0, Bbase, k2);
    MFQ(1, 0);
    if (!lastI) VMC2(); else VMC0();
    BARR();
    // P4: q(1,1); stage K(2i+2) Ah0
    if (!lastI) STG(As, 0, 0, Abase, k2);
    MFQ(1, 1); BARR();
    // P5: compute K(2i+1) q(0,0); stage K(2i+2) Bh1
    RDA(1, 0); RDB(1, 0);
    if (!lastI) STG(Bs, 0, 1, Bbase, k2);
    MFQ(0, 0); BARR();
    // P6: q(0,1); stage K(2i+2) Ah1
    RDB(1, 1);
    if (!lastI) STG(As, 0, 1, Abase, k2);
    MFQ(0, 1); BARR();
    // P7: q(1,0); stage K(2i+3) Bh0; publish K(2i+2)
    RDA(1, 1);
    if (!lastI) STG(Bs, 1, 0, Bbase, k3);
    MFQ(1, 0);
    if (!lastI) VMC2();
    BARR();
    // P8: q(1,1); stage K(2i+3) Ah0
    if (!lastI) {
      STG(As, 1, 0, Abase, k3);
      MFQ(1, 1); BARR();
    } else {
      MFQ(1, 1);
    }
  }
#undef STG
#undef RDA
#undef RDB
#undef MFQ

  if (MODE == 0) {
    if (n0 < 2560) {
      u16* dst; int c0;
      if (n0 < 1280) { dst = preq; c0 = n0; }
      else           { dst = prek; c0 = n0 - 1280; }
#pragma unroll
      for (int mi = 0; mi < 8; mi++)
#pragma unroll
        for (int j = 0; j < 4; j++) {
          const size_t rowo = (size_t)(m0 + wm * 128 + mi * 16 + lq * 4 + j) * E_DIM;
#pragma unroll
          for (int ni = 0; ni < 4; ni++)
            dst[rowo + c0 + wn * 64 + ni * 16 + l16] = f2bf(acc[mi][ni][j]);
        }
    } else {
      const int c0 = n0 - 2560;
#pragma unroll
      for (int mi = 0; mi < 8; mi++)
#pragma unroll
        for (int ni = 0; ni < 4; ni++) {
          ushort4 pkt;
          pkt.x = f2bf(acc[mi][ni][0]); pkt.y = f2bf(acc[mi][ni][1]);
          pkt.z = f2bf(acc[mi][ni][2]); pkt.w = f2bf(acc[mi][ni][3]);
          const size_t off = (size_t)(c0 + wn * 64 + ni * 16 + l16) * T_TOK +
                             (m0 + wm * 128 + mi * 16 + lq * 4);
          *(ushort4*)(vT + off) = pkt;
        }
    }
  } else {
#pragma unroll
    for (int mi = 0; mi < 8; mi++)
#pragma unroll
      for (int j = 0; j < 4; j++) {
        const size_t rowo = (size_t)(m0 + wm * 128 + mi * 16 + lq * 4 + j) * E_DIM;
#pragma unroll
        for (int ni = 0; ni < 4; ni++)
          Cf[rowo + n0 + wn * 64 + ni * 16 + l16] = acc[mi][ni][j];
      }
  }
}

// ---------------- flash attention: swapped-QK 32x32, no-max exp2 softmax ----
// Plain __launch_bounds__(256): VGPR=104, no spills (R12's (256,5) forced
// VGPR 48 -> scratch spills -> 130us; measured-best is unconstrained).
__global__ __launch_bounds__(256) void attn_kernel(const u16* __restrict__ q,
                                                   const u16* __restrict__ k,
                                                   const u16* __restrict__ vT,
                                                   const int* __restrict__ cu,
                                                   u16* __restrict__ o) {
  const int bx = blockIdx.x;
  const int hb = bx % (NH * NSEQ);
  const int qt = bx / (NH * NSEQ);
  const int hh = hb % NH;
  const int b  = hb / NH;
  const int base = cu[b];
  const int nkt  = (cu[b + 1] - base) >> 6;
  const int tid  = threadIdx.x;
  const int wid  = tid >> 6, lane = tid & 63;
  const int l31  = lane & 31, hi = lane >> 5;

  __shared__ u16 Ks[2][64 * 64];
  __shared__ u16 Vs[2][64 * 64];

  const int qrow = base + qt * 128 + wid * 32 + l31;
  bf16x8 qf[4];
#pragma unroll
  for (int kk = 0; kk < 4; kk++)
    qf[kk] = *(const bf16x8*)(q + (size_t)qrow * E_DIM + hh * 64 + kk * 16 + hi * 8);

  f32x16 acc0 = {}, acc1 = {};
  float lrow = 0.f;

  const int r0 = tid >> 3;
  const int chs = tid & 7;
  const int cs0 = (chs ^ (r0 & 7)) << 3;
  const int r1 = r0 + 32;
  const int cs1 = (chs ^ (r1 & 7)) << 3;
  const u16* kg0 = k  + (size_t)(base + r0) * E_DIM + hh * 64 + cs0;
  const u16* kg1 = k  + (size_t)(base + r1) * E_DIM + hh * 64 + cs1;
  const u16* vg0 = vT + (size_t)(hh * 64 + r0) * T_TOK + base + cs0;
  const u16* vg1 = vT + (size_t)(hh * 64 + r1) * T_TOK + base + cs1;
  const int ldsoff = wid * 512;

  gld_lds16(kg0, &Ks[0][ldsoff]);
  gld_lds16(kg1, &Ks[0][2048 + ldsoff]);
  gld_lds16(vg0, &Vs[0][ldsoff]);
  gld_lds16(vg1, &Vs[0][2048 + ldsoff]);
  __syncthreads();

  int cur = 0;
  for (int kt = 0; kt < nkt; kt++) {
    if (kt + 1 < nkt) {
      const size_t ko = (size_t)(kt + 1) * 64 * E_DIM;
      const int vo = (kt + 1) * 64;
      u16* kd = Ks[cur ^ 1];
      u16* vd = Vs[cur ^ 1];
      gld_lds16(kg0 + ko, kd + ldsoff);
      gld_lds16(kg1 + ko, kd + 2048 + ldsoff);
      gld_lds16(vg0 + vo, vd + ldsoff);
      gld_lds16(vg1 + vo, vd + 2048 + ldsoff);
    }
    const u16* Kc = Ks[cur];
    const u16* Vc = Vs[cur];

    f32x16 S0 = {}, S1 = {};
#pragma unroll
    for (int kk = 0; kk < 4; kk++) {
      const int c0 = (((kk << 1) | hi) ^ (l31 & 7)) << 3;
      const bf16x8 kf0 = *(const bf16x8*)(Kc + l31 * 64 + c0);
      const bf16x8 kf1 = *(const bf16x8*)(Kc + (32 + l31) * 64 + c0);
      S0 = __builtin_amdgcn_mfma_f32_32x32x16_bf16(kf0, qf[kk], S0, 0, 0, 0);
      S1 = __builtin_amdgcn_mfma_f32_32x32x16_bf16(kf1, qf[kk], S1, 0, 0, 0);
    }

    float rs0 = 0.f, rs1 = 0.f, rs2 = 0.f, rs3 = 0.f;
#pragma unroll
    for (int r = 0; r < 16; r += 4) {
      S0[r + 0] = exp2f(S0[r + 0]); S0[r + 1] = exp2f(S0[r + 1]);
      S0[r + 2] = exp2f(S0[r + 2]); S0[r + 3] = exp2f(S0[r + 3]);
      rs0 += S0[r + 0]; rs1 += S0[r + 1]; rs2 += S0[r + 2]; rs3 += S0[r + 3];
    }
#pragma unroll
    for (int r = 0; r < 16; r += 4) {
      S1[r + 0] = exp2f(S1[r + 0]); S1[r + 1] = exp2f(S1[r + 1]);
      S1[r + 2] = exp2f(S1[r + 2]); S1[r + 3] = exp2f(S1[r + 3]);
      rs0 += S1[r + 0]; rs1 += S1[r + 1]; rs2 += S1[r + 2]; rs3 += S1[r + 3];
    }
    float rs = (rs0 + rs1) + (rs2 + rs3);
    rs += __shfl_xor(rs, 32);
    lrow += rs;

    u32 pw[4][4];
#pragma unroll
    for (int ks = 0; ks < 4; ks++) {
      const int g = (ks & 1) << 3;
      u32 A0, A1, B0, B1;
      if (ks < 2) {
        A0 = cvtpk(S0[g + 0], S0[g + 1]); A1 = cvtpk(S0[g + 2], S0[g + 3]);
        B0 = cvtpk(S0[g + 4], S0[g + 5]); B1 = cvtpk(S0[g + 6], S0[g + 7]);
      } else {
        A0 = cvtpk(S1[g + 0], S1[g + 1]); A1 = cvtpk(S1[g + 2], S1[g + 3]);
        B0 = cvtpk(S1[g + 4], S1[g + 5]); B1 = cvtpk(S1[g + 6], S1[g + 7]);
      }
      asm("v_permlane32_swap_b32 %0, %1" : "+v"(A0), "+v"(B0));
      asm("v_permlane32_swap_b32 %0, %1" : "+v"(A1), "+v"(B1));
      pw[ks][0] = A0; pw[ks][1] = A1; pw[ks][2] = B0; pw[ks][3] = B1;
    }

#pragma unroll
    for (int ks = 0; ks < 4; ks++) {
      const bf16x8 pa = *(const bf16x8*)&pw[ks][0];
      const int c0 = (((ks << 1) | hi) ^ (l31 & 7)) << 3;
      const bf16x8 vf0 = *(const bf16x8*)(Vc + l31 * 64 + c0);
      const bf16x8 vf1 = *(const bf16x8*)(Vc + (32 + l31) * 64 + c0);
      acc0 = __builtin_amdgcn_mfma_f32_32x32x16_bf16(pa, vf0, acc0, 0, 0, 0);
      acc1 = __builtin_amdgcn_mfma_f32_32x32x16_bf16(pa, vf1, acc1, 0, 0, 0);
    }
    __syncthreads();
    cur ^= 1;
  }

  const float linv = 1.0f / lrow;
  const int tok0 = base + qt * 128 + wid * 32;
#pragma unroll
  for (int r = 0; r < 16; r++) {
    const int qr = (r & 3) + 8 * (r >> 2) + 4 * hi;
    const float ls = __shfl(linv, qr);
    const size_t ro = (size_t)(tok0 + qr) * E_DIM + hh * 64 + l31;
    o[ro]      = f2bf(acc0[r] * ls);
    o[ro + 32] = f2bf(acc1[r] * ls);
  }
}

// ---------------- launch ----------------
extern "C" void kernel_launch(void* const* d_in, const int* in_sizes, int n_in,
                              void* d_out, int out_size, void* d_ws, size_t ws_size,
                              hipStream_t stream) {
  const float* x      = (const float*)d_in[0];
  const int*   cu     = (const int*)d_in[1];
  const float* norm_w = (const float*)d_in[3];
  const float* norm_b = (const float*)d_in[4];
  const float* Wq     = (const float*)d_in[5];
  const float* Wk     = (const float*)d_in[6];
  const float* Wv     = (const float*)d_in[7];
  const float* Wo     = (const float*)d_in[8];
  const float* lnq    = (const float*)d_in[9];
  const float* lnk    = (const float*)d_in[10];
  float* out = (float*)d_out;

  const size_t EE2 = (size_t)E_DIM * E_DIM * 2;
  const size_t TE2 = (size_t)T_TOK * E_DIM * 2;
  char* p = (char*)d_ws;
  u16* wqkv = (u16*)p; p += 3 * EE2;
  u16* wo_b = (u16*)p; p += EE2;
  u16* h_b  = (u16*)p; p += TE2;   // later: attention output
  u16* preq = (u16*)p; p += TE2;
  u16* prek = (u16*)p; p += TE2;
  u16* vT_b = (u16*)p; p += TE2;
  float2* tab = (float2*)p; p += 1024 * 32 * sizeof(float2);

  prep_kernel<<<CVT_BLOCKS + 128, 256, 0, stream>>>(Wq, Wk, Wv, Wo, wqkv, wo_b, tab);
  ln_x_kernel<<<T_TOK, 320, 0, stream>>>(x, norm_w, norm_b, h_b);

  // QKV: M=8192, N=3840 -> 32 x 15 = 480 blocks
  gemm256<0, E_DIM><<<480, 512, 0, stream>>>(h_b, wqkv, preq, prek, vT_b, nullptr);

  // fused q+k LN+RoPE (q pre-scaled by 0.125*log2e)
  ln_rope2_kernel<<<2 * T_TOK, 320, 0, stream>>>(preq, prek, lnq, lnk, cu, tab, preq, prek);

  attn_kernel<<<8 * NH * NSEQ, 256, 0, stream>>>(preq, prek, vT_b, cu, h_b);

  // OUT: M=8192, N=1280 -> 32 x 5 = 160 blocks
  gemm256<1, E_DIM><<<160, 512, 0, stream>>>(h_b, wo_b, nullptr, nullptr, nullptr, out);
}

// Round 14
// 252.030 us; speedup vs baseline: 1.1883x; 1.0011x over previous
//
#include <hip/hip_runtime.h>
#include <hip/hip_bf16.h>
#include <math.h>

#define NH 20
#define HD 64
#define E_DIM 1280
#define T_TOK 8192
#define NSEQ 8
#define N4 (E_DIM * E_DIM / 4)

#define SCALE_LOG2 0.1803368801111204f   // 0.125 * log2(e)

typedef unsigned short u16;
typedef unsigned int u32;
typedef __attribute__((ext_vector_type(8))) short bf16x8;
typedef __attribute__((ext_vector_type(4))) float f32x4;
typedef __attribute__((ext_vector_type(16))) float f32x16;

__device__ __forceinline__ float bf2f(u16 h) {
  union { float f; unsigned u; } c; c.u = ((unsigned)h) << 16; return c.f;
}
__device__ __forceinline__ u16 f2bf(float f) {
  union { float f; unsigned u; } c; c.f = f;
  unsigned u = c.u;
  return (u16)((u + 0x7fffu + ((u >> 16) & 1u)) >> 16);
}
__device__ __forceinline__ u32 cvtpk(float lo, float hi) {
  u32 r;
  asm("v_cvt_pk_bf16_f32 %0, %1, %2" : "=v"(r) : "v"(lo), "v"(hi));
  return r;
}

__device__ __forceinline__ void gld_lds16(const void* g, void* l) {
  __builtin_amdgcn_global_load_lds((const __attribute__((address_space(1))) void*)g,
                                   (__attribute__((address_space(3))) void*)l,
                                   16, 0, 0);
}

#define BARR() __builtin_amdgcn_s_barrier()
#define VMC8() asm volatile("s_waitcnt vmcnt(8)" ::: "memory")
#define VMC6() asm volatile("s_waitcnt vmcnt(6)" ::: "memory")
#define VMC4() asm volatile("s_waitcnt vmcnt(4)" ::: "memory")
#define VMC2() asm volatile("s_waitcnt vmcnt(2)" ::: "memory")
#define VMC0() asm volatile("s_waitcnt vmcnt(0)" ::: "memory")

// -------- weights fp32 -> bf16 + RoPE table, one launch --------
// blocks [0, 6400): cvt 4*N4 float4s; blocks [6400, 6528): rope table.
#define CVT_BLOCKS 6400
__global__ __launch_bounds__(256) void prep_kernel(const float* __restrict__ Wq,
                                                   const float* __restrict__ Wk,
                                                   const float* __restrict__ Wv,
                                                   const float* __restrict__ Wo,
                                                   u16* __restrict__ wqkv,
                                                   u16* __restrict__ wo,
                                                   float2* __restrict__ tab) {
  if (blockIdx.x < CVT_BLOCKS) {
    int i = blockIdx.x * 256 + threadIdx.x;
    if (i >= 4 * N4) return;
    int r = i / N4;
    int l = i - r * N4;
    const float* src = (r == 0) ? Wq : (r == 1) ? Wk : (r == 2) ? Wv : Wo;
    float4 v = ((const float4*)src)[l];
    ushort4 ov;
    ov.x = f2bf(v.x); ov.y = f2bf(v.y); ov.z = f2bf(v.z); ov.w = f2bf(v.w);
    if (r < 3) ((ushort4*)wqkv)[(size_t)r * N4 + l] = ov;
    else       ((ushort4*)wo)[l] = ov;
  } else {
    int i = (blockIdx.x - CVT_BLOCKS) * 256 + threadIdx.x;   // 0..32767
    if (i >= 1024 * 32) return;
    int pos = i >> 5, dm = i & 31;
    float freq = exp2f(-(float)dm * (13.287712379549449f / 32.0f));
    float f = (float)pos * freq;
    tab[i] = make_float2(cosf(f), sinf(f));
  }
}

// ---------------- pre-norm: h = LN(x)*w + b, bf16 out ----------------
__global__ __launch_bounds__(320) void ln_x_kernel(const float* __restrict__ x,
                                                   const float* __restrict__ w,
                                                   const float* __restrict__ b,
                                                   u16* __restrict__ h) {
  const int row = blockIdx.x;
  const int tid = threadIdx.x;
  const float4 xv = ((const float4*)(x + (size_t)row * E_DIM))[tid];
  float s  = xv.x + xv.y + xv.z + xv.w;
  float s2 = xv.x*xv.x + xv.y*xv.y + xv.z*xv.z + xv.w*xv.w;
#pragma unroll
  for (int m = 1; m < 64; m <<= 1) { s += __shfl_xor(s, m); s2 += __shfl_xor(s2, m); }
  __shared__ float ss[5], ss2[5];
  if ((tid & 63) == 0) { ss[tid >> 6] = s; ss2[tid >> 6] = s2; }
  __syncthreads();
  s  = ss[0] + ss[1] + ss[2] + ss[3] + ss[4];
  s2 = ss2[0] + ss2[1] + ss2[2] + ss2[3] + ss2[4];
  const float mean = s * (1.0f / E_DIM);
  const float var  = s2 * (1.0f / E_DIM) - mean * mean;
  const float rstd = rsqrtf(var + 1e-5f);
  const float4 wv = ((const float4*)w)[tid];
  const float4 bv = ((const float4*)b)[tid];
  ushort4 o;
  o.x = f2bf((xv.x - mean) * rstd * wv.x + bv.x);
  o.y = f2bf((xv.y - mean) * rstd * wv.y + bv.y);
  o.z = f2bf((xv.z - mean) * rstd * wv.z + bv.z);
  o.w = f2bf((xv.w - mean) * rstd * wv.w + bv.w);
  ((ushort4*)(h + (size_t)row * E_DIM))[tid] = o;
}

// ------- fused LN (no bias) + RoPE for q and k in one launch -------------
__global__ __launch_bounds__(320) void ln_rope2_kernel(const u16* __restrict__ preq,
                                                       const u16* __restrict__ prek,
                                                       const float* __restrict__ wq,
                                                       const float* __restrict__ wk,
                                                       const int* __restrict__ cu,
                                                       const float2* __restrict__ tab,
                                                       u16* __restrict__ outq,
                                                       u16* __restrict__ outk) {
  const int sel = blockIdx.x >> 13;
  const int row = blockIdx.x & (T_TOK - 1);
  const u16* pre = sel ? prek : preq;
  const float* w = sel ? wk : wq;
  u16* outp = sel ? outk : outq;
  const float oscale = sel ? 1.0f : SCALE_LOG2;
  const int tid = threadIdx.x;
  __shared__ float y[E_DIM];
  const ushort4 qv = ((const ushort4*)(pre + (size_t)row * E_DIM))[tid];
  float v0 = bf2f(qv.x), v1 = bf2f(qv.y), v2 = bf2f(qv.z), v3 = bf2f(qv.w);
  float s  = v0 + v1 + v2 + v3;
  float s2 = v0*v0 + v1*v1 + v2*v2 + v3*v3;
#pragma unroll
  for (int m = 1; m < 64; m <<= 1) { s += __shfl_xor(s, m); s2 += __shfl_xor(s2, m); }
  __shared__ float ss[5], ss2[5];
  if ((tid & 63) == 0) { ss[tid >> 6] = s; ss2[tid >> 6] = s2; }
  __syncthreads();
  s  = ss[0] + ss[1] + ss[2] + ss[3] + ss[4];
  s2 = ss2[0] + ss2[1] + ss2[2] + ss2[3] + ss2[4];
  const float mean = s * (1.0f / E_DIM);
  const float var  = s2 * (1.0f / E_DIM) - mean * mean;
  const float rstd = rsqrtf(var + 1e-5f);
  const int e0 = tid * 4;
  float4 wv = ((const float4*)w)[tid];
  wv.x *= oscale; wv.y *= oscale; wv.z *= oscale; wv.w *= oscale;
  y[e0 + 0] = (v0 - mean) * rstd * wv.x;
  y[e0 + 1] = (v1 - mean) * rstd * wv.y;
  y[e0 + 2] = (v2 - mean) * rstd * wv.z;
  y[e0 + 3] = (v3 - mean) * rstd * wv.w;
  __syncthreads();
  int seg = 0;
#pragma unroll
  for (int bb = 1; bb < NSEQ + 1; bb++) if (cu[bb] <= row) seg = bb;
  const int pos = row - cu[seg];
  const int d0 = e0 & 63;
  const int hbase = e0 - d0;
  const float4* tp = (const float4*)(tab + pos * 32 + (d0 & 31));
  const float4 t0 = tp[0], t1 = tp[1];
  const float cs_[4] = {t0.x, t0.z, t1.x, t1.z};
  const float sn_[4] = {t0.y, t0.w, t1.y, t1.w};
  const bool lo = (d0 < 32);
  ushort4 o;
#pragma unroll
  for (int i = 0; i < 4; i++) {
    const int d = d0 + i;
    float r;
    if (lo) r = y[hbase + d] * cs_[i] - y[hbase + d + 32] * sn_[i];
    else    r = y[hbase + d] * cs_[i] + y[hbase + d - 32] * sn_[i];
    ((u16*)&o)[i] = f2bf(r);
  }
  ((ushort4*)(outp + (size_t)row * E_DIM))[tid] = o;
}

// ---------------- 256x256 8-phase GEMM, uniform-depth vmcnt(8) pipeline ---
// R9 base (1 barrier/phase, compiler-scheduled reads) + deepened prefetch:
// vmcnt(8) at EVERY phase end keeps 4 half-tiles in flight; each load is
// drained exactly 4 phases (~2400cy) after issue, one barrier before its
// first read (verified per-slot). Last iter overrides: P3/P4/P5/P6 ->
// vmcnt(6/4/2/0). Prologue VMC4 publishes K0, leaves K1-h0 in flight.
template <int MODE, int K>
__global__ __launch_bounds__(512) void gemm256(const u16* __restrict__ A,
                                               const u16* __restrict__ B,
                                               u16* __restrict__ preq,
                                               u16* __restrict__ prek,
                                               u16* __restrict__ vT,
                                               float* __restrict__ Cf) {
  __shared__ u16 As[2][16384];
  __shared__ u16 Bs[2][16384];
  const int tid = threadIdx.x;
  const int wid = tid >> 6, lane = tid & 63;
  const int l16 = lane & 15, lq = lane >> 4;
  const int wm = wid >> 2, wn = wid & 3;
  const int bm = blockIdx.x & 31;            // M = 8192 -> 32 tiles
  const int bn = blockIdx.x >> 5;
  const int m0 = bm << 8, n0 = bn << 8;
  const int sw = l16 & 7;

  const int row0 = tid >> 3;                 // 0..63
  const int ch0 = ((tid & 7) ^ (row0 & 7)) << 3;
  const u16* Abase = A + (size_t)(m0 + row0) * K + ch0;
  const u16* Bbase = B + (size_t)(n0 + row0) * K + ch0;
  const int dst0 = tid * 8;

  const int CA = (wm * 128 + l16) * 64;
  const int CB = (wn * 64 + l16) * 64;
  const int ch_0 = ((0 | lq) ^ sw) << 3;
  const int ch_1 = ((4 | lq) ^ sw) << 3;

  f32x4 acc[8][4] = {};
  bf16x8 aF[4][2], bF[2][2][2];

#define STG(Larr, bufp, hh, gbase, kt) do {                                     \
    const u16* g_ = (gbase) + (size_t)(hh) * 128 * K + (size_t)(kt) * 64;       \
    gld_lds16(g_, &Larr[bufp][(hh) * 8192 + dst0]);                             \
    gld_lds16(g_ + (size_t)64 * K, &Larr[bufp][(hh) * 8192 + dst0 + 4096]);     \
  } while (0)

#define RDA(bufp, a) do {                                                       \
    _Pragma("unroll") for (int mb = 0; mb < 4; mb++) {                          \
      aF[mb][0] = *(const bf16x8*)(&As[bufp][CA + (a) * 4096 + mb * 1024 + ch_0]); \
      aF[mb][1] = *(const bf16x8*)(&As[bufp][CA + (a) * 4096 + mb * 1024 + ch_1]); \
    } } while (0)

#define RDB(bufp, b) do {                                                       \
    _Pragma("unroll") for (int nb = 0; nb < 2; nb++) {                          \
      bF[b][nb][0] = *(const bf16x8*)(&Bs[bufp][CB + (b) * 2048 + nb * 1024 + ch_0]); \
      bF[b][nb][1] = *(const bf16x8*)(&Bs[bufp][CB + (b) * 2048 + nb * 1024 + ch_1]); \
    } } while (0)

#define MFQ(a, b) do {                                                          \
    __builtin_amdgcn_s_setprio(1);                                              \
    _Pragma("unroll") for (int mb = 0; mb < 4; mb++)                            \
    _Pragma("unroll") for (int nb = 0; nb < 2; nb++)                            \
    _Pragma("unroll") for (int kk = 0; kk < 2; kk++)                            \
      acc[(a) * 4 + mb][(b) * 2 + nb] = __builtin_amdgcn_mfma_f32_16x16x32_bf16( \
          aF[mb][kk], bF[b][nb][kk], acc[(a) * 4 + mb][(b) * 2 + nb], 0, 0, 0); \
    __builtin_amdgcn_s_setprio(0); } while (0)

  STG(Bs, 0, 0, Bbase, 0);
  STG(As, 0, 0, Abase, 0);
  STG(Bs, 0, 1, Bbase, 0);
  STG(As, 0, 1, Abase, 0);
  STG(Bs, 1, 0, Bbase, 1);
  STG(As, 1, 0, Abase, 1);
  VMC4();
  BARR();

  const int NIT = K / 128;
  for (int i = 0; i < NIT; i++) {
    const bool lastI = (i == NIT - 1);
    const int k1 = 2 * i + 1, k2 = 2 * i + 2, k3 = 2 * i + 3;
    // P1: compute K(2i) q(0,0); stage K(2i+1) Bh1
    RDA(0, 0); RDB(0, 0);
    STG(Bs, 1, 1, Bbase, k1);
    MFQ(0, 0); VMC8(); BARR();
    // P2: q(0,1); stage K(2i+1) Ah1
    RDB(0, 1);
    STG(As, 1, 1, Abase, k1);
    MFQ(0, 1); VMC8(); BARR();
    // P3: q(1,0); stage K(2i+2) Bh0
    RDA(0, 1);
    if (!lastI) STG(Bs, 0, 0, Bbase, k2);
    MFQ(1, 0);
    if (!lastI) VMC8(); else VMC6();
    BARR();
    // P4: q(1,1); stage K(2i+2) Ah0
    if (!lastI) STG(As, 0, 0, Abase, k2);
    MFQ(1, 1);
    if (!lastI) VMC8(); else VMC4();
    BARR();
    // P5: compute K(2i+1) q(0,0); stage K(2i+2) Bh1
    RDA(1, 0); RDB(1, 0);
    if (!lastI) STG(Bs, 0, 1, Bbase, k2);
    MFQ(0, 0);
    if (!lastI) VMC8(); else VMC2();
    BARR();
    // P6: q(0,1); stage K(2i+2) Ah1
    RDB(1, 1);
    if (!lastI) STG(As, 0, 1, Abase, k2);
    MFQ(0, 1);
    if (!lastI) VMC8(); else VMC0();
    BARR();
    // P7: q(1,0); stage K(2i+3) Bh0
    RDA(1, 1);
    if (!lastI) STG(Bs, 1, 0, Bbase, k3);
    MFQ(1, 0);
    if (!lastI) VMC8();
    BARR();
    // P8: q(1,1); stage K(2i+3) Ah0
    if (!lastI) {
      STG(As, 1, 0, Abase, k3);
      MFQ(1, 1); VMC8(); BARR();
    } else {
      MFQ(1, 1);
    }
  }
#undef STG
#undef RDA
#undef RDB
#undef MFQ

  if (MODE == 0) {
    if (n0 < 2560) {
      u16* dst; int c0;
      if (n0 < 1280) { dst = preq; c0 = n0; }
      else           { dst = prek; c0 = n0 - 1280; }
#pragma unroll
      for (int mi = 0; mi < 8; mi++)
#pragma unroll
        for (int j = 0; j < 4; j++) {
          const size_t rowo = (size_t)(m0 + wm * 128 + mi * 16 + lq * 4 + j) * E_DIM;
#pragma unroll
          for (int ni = 0; ni < 4; ni++)
            dst[rowo + c0 + wn * 64 + ni * 16 + l16] = f2bf(acc[mi][ni][j]);
        }
    } else {
      const int c0 = n0 - 2560;
#pragma unroll
      for (int mi = 0; mi < 8; mi++)
#pragma unroll
        for (int ni = 0; ni < 4; ni++) {
          ushort4 pkt;
          pkt.x = f2bf(acc[mi][ni][0]); pkt.y = f2bf(acc[mi][ni][1]);
          pkt.z = f2bf(acc[mi][ni][2]); pkt.w = f2bf(acc[mi][ni][3]);
          const size_t off = (size_t)(c0 + wn * 64 + ni * 16 + l16) * T_TOK +
                             (m0 + wm * 128 + mi * 16 + lq * 4);
          *(ushort4*)(vT + off) = pkt;
        }
    }
  } else {
#pragma unroll
    for (int mi = 0; mi < 8; mi++)
#pragma unroll
      for (int j = 0; j < 4; j++) {
        const size_t rowo = (size_t)(m0 + wm * 128 + mi * 16 + lq * 4 + j) * E_DIM;
#pragma unroll
        for (int ni = 0; ni < 4; ni++)
          Cf[rowo + n0 + wn * 64 + ni * 16 + l16] = acc[mi][ni][j];
      }
  }
}

// ---------------- flash attention: swapped-QK 32x32, no-max exp2 softmax ----
// Plain __launch_bounds__(256): VGPR=104, no spills (R12's (256,5) forced
// VGPR 48 -> scratch spills -> 130us; measured-best is unconstrained).
__global__ __launch_bounds__(256) void attn_kernel(const u16* __restrict__ q,
                                                   const u16* __restrict__ k,
                                                   const u16* __restrict__ vT,
                                                   const int* __restrict__ cu,
                                                   u16* __restrict__ o) {
  const int bx = blockIdx.x;
  const int hb = bx % (NH * NSEQ);
  const int qt = bx / (NH * NSEQ);
  const int hh = hb % NH;
  const int b  = hb / NH;
  const int base = cu[b];
  const int nkt  = (cu[b + 1] - base) >> 6;
  const int tid  = threadIdx.x;
  const int wid  = tid >> 6, lane = tid & 63;
  const int l31  = lane & 31, hi = lane >> 5;

  __shared__ u16 Ks[2][64 * 64];
  __shared__ u16 Vs[2][64 * 64];

  const int qrow = base + qt * 128 + wid * 32 + l31;
  bf16x8 qf[4];
#pragma unroll
  for (int kk = 0; kk < 4; kk++)
    qf[kk] = *(const bf16x8*)(q + (size_t)qrow * E_DIM + hh * 64 + kk * 16 + hi * 8);

  f32x16 acc0 = {}, acc1 = {};
  float lrow = 0.f;

  const int r0 = tid >> 3;
  const int chs = tid & 7;
  const int cs0 = (chs ^ (r0 & 7)) << 3;
  const int r1 = r0 + 32;
  const int cs1 = (chs ^ (r1 & 7)) << 3;
  const u16* kg0 = k  + (size_t)(base + r0) * E_DIM + hh * 64 + cs0;
  const u16* kg1 = k  + (size_t)(base + r1) * E_DIM + hh * 64 + cs1;
  const u16* vg0 = vT + (size_t)(hh * 64 + r0) * T_TOK + base + cs0;
  const u16* vg1 = vT + (size_t)(hh * 64 + r1) * T_TOK + base + cs1;
  const int ldsoff = wid * 512;

  gld_lds16(kg0, &Ks[0][ldsoff]);
  gld_lds16(kg1, &Ks[0][2048 + ldsoff]);
  gld_lds16(vg0, &Vs[0][ldsoff]);
  gld_lds16(vg1, &Vs[0][2048 + ldsoff]);
  __syncthreads();

  int cur = 0;
  for (int kt = 0; kt < nkt; kt++) {
    if (kt + 1 < nkt) {
      const size_t ko = (size_t)(kt + 1) * 64 * E_DIM;
      const int vo = (kt + 1) * 64;
      u16* kd = Ks[cur ^ 1];
      u16* vd = Vs[cur ^ 1];
      gld_lds16(kg0 + ko, kd + ldsoff);
      gld_lds16(kg1 + ko, kd + 2048 + ldsoff);
      gld_lds16(vg0 + vo, vd + ldsoff);
      gld_lds16(vg1 + vo, vd + 2048 + ldsoff);
    }
    const u16* Kc = Ks[cur];
    const u16* Vc = Vs[cur];

    f32x16 S0 = {}, S1 = {};
#pragma unroll
    for (int kk = 0; kk < 4; kk++) {
      const int c0 = (((kk << 1) | hi) ^ (l31 & 7)) << 3;
      const bf16x8 kf0 = *(const bf16x8*)(Kc + l31 * 64 + c0);
      const bf16x8 kf1 = *(const bf16x8*)(Kc + (32 + l31) * 64 + c0);
      S0 = __builtin_amdgcn_mfma_f32_32x32x16_bf16(kf0, qf[kk], S0, 0, 0, 0);
      S1 = __builtin_amdgcn_mfma_f32_32x32x16_bf16(kf1, qf[kk], S1, 0, 0, 0);
    }

    float rs0 = 0.f, rs1 = 0.f, rs2 = 0.f, rs3 = 0.f;
#pragma unroll
    for (int r = 0; r < 16; r += 4) {
      S0[r + 0] = exp2f(S0[r + 0]); S0[r + 1] = exp2f(S0[r + 1]);
      S0[r + 2] = exp2f(S0[r + 2]); S0[r + 3] = exp2f(S0[r + 3]);
      rs0 += S0[r + 0]; rs1 += S0[r + 1]; rs2 += S0[r + 2]; rs3 += S0[r + 3];
    }
#pragma unroll
    for (int r = 0; r < 16; r += 4) {
      S1[r + 0] = exp2f(S1[r + 0]); S1[r + 1] = exp2f(S1[r + 1]);
      S1[r + 2] = exp2f(S1[r + 2]); S1[r + 3] = exp2f(S1[r + 3]);
      rs0 += S1[r + 0]; rs1 += S1[r + 1]; rs2 += S1[r + 2]; rs3 += S1[r + 3];
    }
    float rs = (rs0 + rs1) + (rs2 + rs3);
    rs += __shfl_xor(rs, 32);
    lrow += rs;

    u32 pw[4][4];
#pragma unroll
    for (int ks = 0; ks < 4; ks++) {
      const int g = (ks & 1) << 3;
      u32 A0, A1, B0, B1;
      if (ks < 2) {
        A0 = cvtpk(S0[g + 0], S0[g + 1]); A1 = cvtpk(S0[g + 2], S0[g + 3]);
        B0 = cvtpk(S0[g + 4], S0[g + 5]); B1 = cvtpk(S0[g + 6], S0[g + 7]);
      } else {
        A0 = cvtpk(S1[g + 0], S1[g + 1]); A1 = cvtpk(S1[g + 2], S1[g + 3]);
        B0 = cvtpk(S1[g + 4], S1[g + 5]); B1 = cvtpk(S1[g + 6], S1[g + 7]);
      }
      asm("v_permlane32_swap_b32 %0, %1" : "+v"(A0), "+v"(B0));
      asm("v_permlane32_swap_b32 %0, %1" : "+v"(A1), "+v"(B1));
      pw[ks][0] = A0; pw[ks][1] = A1; pw[ks][2] = B0; pw[ks][3] = B1;
    }

#pragma unroll
    for (int ks = 0; ks < 4; ks++) {
      const bf16x8 pa = *(const bf16x8*)&pw[ks][0];
      const int c0 = (((ks << 1) | hi) ^ (l31 & 7)) << 3;
      const bf16x8 vf0 = *(const bf16x8*)(Vc + l31 * 64 + c0);
      const bf16x8 vf1 = *(const bf16x8*)(Vc + (32 + l31) * 64 + c0);
      acc0 = __builtin_amdgcn_mfma_f32_32x32x16_bf16(pa, vf0, acc0, 0, 0, 0);
      acc1 = __builtin_amdgcn_mfma_f32_32x32x16_bf16(pa, vf1, acc1, 0, 0, 0);
    }
    __syncthreads();
    cur ^= 1;
  }

  const float linv = 1.0f / lrow;
  const int tok0 = base + qt * 128 + wid * 32;
#pragma unroll
  for (int r = 0; r < 16; r++) {
    const int qr = (r & 3) + 8 * (r >> 2) + 4 * hi;
    const float ls = __shfl(linv, qr);
    const size_t ro = (size_t)(tok0 + qr) * E_DIM + hh * 64 + l31;
    o[ro]      = f2bf(acc0[r] * ls);
    o[ro + 32] = f2bf(acc1[r] * ls);
  }
}

// ---------------- launch ----------------
extern "C" void kernel_launch(void* const* d_in, const int* in_sizes, int n_in,
                              void* d_out, int out_size, void* d_ws, size_t ws_size,
                              hipStream_t stream) {
  const float* x      = (const float*)d_in[0];
  const int*   cu     = (const int*)d_in[1];
  const float* norm_w = (const float*)d_in[3];
  const float* norm_b = (const float*)d_in[4];
  const float* Wq     = (const float*)d_in[5];
  const float* Wk     = (const float*)d_in[6];
  const float* Wv     = (const float*)d_in[7];
  const float* Wo     = (const float*)d_in[8];
  const float* lnq    = (const float*)d_in[9];
  const float* lnk    = (const float*)d_in[10];
  float* out = (float*)d_out;

  const size_t EE2 = (size_t)E_DIM * E_DIM * 2;
  const size_t TE2 = (size_t)T_TOK * E_DIM * 2;
  char* p = (char*)d_ws;
  u16* wqkv = (u16*)p; p += 3 * EE2;
  u16* wo_b = (u16*)p; p += EE2;
  u16* h_b  = (u16*)p; p += TE2;   // later: attention output
  u16* preq = (u16*)p; p += TE2;
  u16* prek = (u16*)p; p += TE2;
  u16* vT_b = (u16*)p; p += TE2;
  float2* tab = (float2*)p; p += 1024 * 32 * sizeof(float2);

  prep_kernel<<<CVT_BLOCKS + 128, 256, 0, stream>>>(Wq, Wk, Wv, Wo, wqkv, wo_b, tab);
  ln_x_kernel<<<T_TOK, 320, 0, stream>>>(x, norm_w, norm_b, h_b);

  // QKV: M=8192, N=3840 -> 32 x 15 = 480 blocks
  gemm256<0, E_DIM><<<480, 512, 0, stream>>>(h_b, wqkv, preq, prek, vT_b, nullptr);

  // fused q+k LN+RoPE (q pre-scaled by 0.125*log2e)
  ln_rope2_kernel<<<2 * T_TOK, 320, 0, stream>>>(preq, prek, lnq, lnk, cu, tab, preq, prek);

  attn_kernel<<<8 * NH * NSEQ, 256, 0, stream>>>(preq, prek, vT_b, cu, h_b);

  // OUT: M=8192, N=1280 -> 32 x 5 = 160 blocks
  gemm256<1, E_DIM><<<160, 512, 0, stream>>>(h_b, wo_b, nullptr, nullptr, nullptr, out);
}

// Round 15
// 250.047 us; speedup vs baseline: 1.1977x; 1.0079x over previous
//
#include <hip/hip_runtime.h>
#include <hip/hip_bf16.h>
#include <math.h>

#define NH 20
#define HD 64
#define E_DIM 1280
#define T_TOK 8192
#define NSEQ 8
#define N4 (E_DIM * E_DIM / 4)

#define SCALE_LOG2 0.1803368801111204f   // 0.125 * log2(e)

typedef unsigned short u16;
typedef unsigned int u32;
typedef __attribute__((ext_vector_type(8))) short bf16x8;
typedef __attribute__((ext_vector_type(4))) float f32x4;
typedef __attribute__((ext_vector_type(16))) float f32x16;

__device__ __forceinline__ float bf2f(u16 h) {
  union { float f; unsigned u; } c; c.u = ((unsigned)h) << 16; return c.f;
}
__device__ __forceinline__ u16 f2bf(float f) {
  union { float f; unsigned u; } c; c.f = f;
  unsigned u = c.u;
  return (u16)((u + 0x7fffu + ((u >> 16) & 1u)) >> 16);
}
__device__ __forceinline__ u32 cvtpk(float lo, float hi) {
  u32 r;
  asm("v_cvt_pk_bf16_f32 %0, %1, %2" : "=v"(r) : "v"(lo), "v"(hi));
  return r;
}

__device__ __forceinline__ void gld_lds16(const void* g, void* l) {
  __builtin_amdgcn_global_load_lds((const __attribute__((address_space(1))) void*)g,
                                   (__attribute__((address_space(3))) void*)l,
                                   16, 0, 0);
}

#define BARR() __builtin_amdgcn_s_barrier()
#define VMC8() asm volatile("s_waitcnt vmcnt(8)" ::: "memory")
#define VMC6() asm volatile("s_waitcnt vmcnt(6)" ::: "memory")
#define VMC4() asm volatile("s_waitcnt vmcnt(4)" ::: "memory")
#define VMC2() asm volatile("s_waitcnt vmcnt(2)" ::: "memory")
#define VMC0() asm volatile("s_waitcnt vmcnt(0)" ::: "memory")

// -------- fused: weights fp32->bf16 + RoPE table + pre-norm LN(x), 1 launch.
// 320 threads. blocks [0,5120): cvt (4*N4 = 1,638,400 float4 / 320 = 5120
// exact); [5120,5223): rope table (32768 items, bound-checked);
// [5223, 5223+8192): ln_x rows. All branches block-uniform.
#define CVT_B 5120
#define TAB_B 103
#define PREP_GRID (CVT_B + TAB_B + T_TOK)
__global__ __launch_bounds__(320) void prep_ln_kernel(
    const float* __restrict__ Wq, const float* __restrict__ Wk,
    const float* __restrict__ Wv, const float* __restrict__ Wo,
    u16* __restrict__ wqkv, u16* __restrict__ wo, float2* __restrict__ tab,
    const float* __restrict__ x, const float* __restrict__ nw,
    const float* __restrict__ nb, u16* __restrict__ h) {
  const int bx = blockIdx.x;
  const int tid = threadIdx.x;
  __shared__ float ss[5], ss2[5];
  if (bx < CVT_B) {
    int i = bx * 320 + tid;                  // < 4*N4 exactly
    int r = i / N4;
    int l = i - r * N4;
    const float* src = (r == 0) ? Wq : (r == 1) ? Wk : (r == 2) ? Wv : Wo;
    float4 v = ((const float4*)src)[l];
    ushort4 ov;
    ov.x = f2bf(v.x); ov.y = f2bf(v.y); ov.z = f2bf(v.z); ov.w = f2bf(v.w);
    if (r < 3) ((ushort4*)wqkv)[(size_t)r * N4 + l] = ov;
    else       ((ushort4*)wo)[l] = ov;
  } else if (bx < CVT_B + TAB_B) {
    int i = (bx - CVT_B) * 320 + tid;        // 0..32767
    if (i >= 1024 * 32) return;
    int pos = i >> 5, dm = i & 31;
    float freq = exp2f(-(float)dm * (13.287712379549449f / 32.0f));
    float f = (float)pos * freq;
    tab[i] = make_float2(cosf(f), sinf(f));
  } else {
    const int row = bx - (CVT_B + TAB_B);    // 0..8191
    const float4 xv = ((const float4*)(x + (size_t)row * E_DIM))[tid];
    float s  = xv.x + xv.y + xv.z + xv.w;
    float s2 = xv.x*xv.x + xv.y*xv.y + xv.z*xv.z + xv.w*xv.w;
#pragma unroll
    for (int m = 1; m < 64; m <<= 1) { s += __shfl_xor(s, m); s2 += __shfl_xor(s2, m); }
    if ((tid & 63) == 0) { ss[tid >> 6] = s; ss2[tid >> 6] = s2; }
    __syncthreads();
    s  = ss[0] + ss[1] + ss[2] + ss[3] + ss[4];
    s2 = ss2[0] + ss2[1] + ss2[2] + ss2[3] + ss2[4];
    const float mean = s * (1.0f / E_DIM);
    const float var  = s2 * (1.0f / E_DIM) - mean * mean;
    const float rstd = rsqrtf(var + 1e-5f);
    const float4 wv = ((const float4*)nw)[tid];
    const float4 bv = ((const float4*)nb)[tid];
    ushort4 o;
    o.x = f2bf((xv.x - mean) * rstd * wv.x + bv.x);
    o.y = f2bf((xv.y - mean) * rstd * wv.y + bv.y);
    o.z = f2bf((xv.z - mean) * rstd * wv.z + bv.z);
    o.w = f2bf((xv.w - mean) * rstd * wv.w + bv.w);
    ((ushort4*)(h + (size_t)row * E_DIM))[tid] = o;
  }
}

// ------- fused LN (no bias) + RoPE for q and k in one launch -------------
__global__ __launch_bounds__(320) void ln_rope2_kernel(const u16* __restrict__ preq,
                                                       const u16* __restrict__ prek,
                                                       const float* __restrict__ wq,
                                                       const float* __restrict__ wk,
                                                       const int* __restrict__ cu,
                                                       const float2* __restrict__ tab,
                                                       u16* __restrict__ outq,
                                                       u16* __restrict__ outk) {
  const int sel = blockIdx.x >> 13;
  const int row = blockIdx.x & (T_TOK - 1);
  const u16* pre = sel ? prek : preq;
  const float* w = sel ? wk : wq;
  u16* outp = sel ? outk : outq;
  const float oscale = sel ? 1.0f : SCALE_LOG2;
  const int tid = threadIdx.x;
  __shared__ float y[E_DIM];
  const ushort4 qv = ((const ushort4*)(pre + (size_t)row * E_DIM))[tid];
  float v0 = bf2f(qv.x), v1 = bf2f(qv.y), v2 = bf2f(qv.z), v3 = bf2f(qv.w);
  float s  = v0 + v1 + v2 + v3;
  float s2 = v0*v0 + v1*v1 + v2*v2 + v3*v3;
#pragma unroll
  for (int m = 1; m < 64; m <<= 1) { s += __shfl_xor(s, m); s2 += __shfl_xor(s2, m); }
  __shared__ float ss[5], ss2[5];
  if ((tid & 63) == 0) { ss[tid >> 6] = s; ss2[tid >> 6] = s2; }
  __syncthreads();
  s  = ss[0] + ss[1] + ss[2] + ss[3] + ss[4];
  s2 = ss2[0] + ss2[1] + ss2[2] + ss2[3] + ss2[4];
  const float mean = s * (1.0f / E_DIM);
  const float var  = s2 * (1.0f / E_DIM) - mean * mean;
  const float rstd = rsqrtf(var + 1e-5f);
  const int e0 = tid * 4;
  float4 wv = ((const float4*)w)[tid];
  wv.x *= oscale; wv.y *= oscale; wv.z *= oscale; wv.w *= oscale;
  y[e0 + 0] = (v0 - mean) * rstd * wv.x;
  y[e0 + 1] = (v1 - mean) * rstd * wv.y;
  y[e0 + 2] = (v2 - mean) * rstd * wv.z;
  y[e0 + 3] = (v3 - mean) * rstd * wv.w;
  __syncthreads();
  int seg = 0;
#pragma unroll
  for (int bb = 1; bb < NSEQ + 1; bb++) if (cu[bb] <= row) seg = bb;
  const int pos = row - cu[seg];
  const int d0 = e0 & 63;
  const int hbase = e0 - d0;
  const float4* tp = (const float4*)(tab + pos * 32 + (d0 & 31));
  const float4 t0 = tp[0], t1 = tp[1];
  const float cs_[4] = {t0.x, t0.z, t1.x, t1.z};
  const float sn_[4] = {t0.y, t0.w, t1.y, t1.w};
  const bool lo = (d0 < 32);
  ushort4 o;
#pragma unroll
  for (int i = 0; i < 4; i++) {
    const int d = d0 + i;
    float r;
    if (lo) r = y[hbase + d] * cs_[i] - y[hbase + d + 32] * sn_[i];
    else    r = y[hbase + d] * cs_[i] + y[hbase + d - 32] * sn_[i];
    ((u16*)&o)[i] = f2bf(r);
  }
  ((ushort4*)(outp + (size_t)row * E_DIM))[tid] = o;
}

// ---------------- 256x256 8-phase GEMM (R14 schedule, measured-best) ------
template <int MODE, int K>
__global__ __launch_bounds__(512) void gemm256(const u16* __restrict__ A,
                                               const u16* __restrict__ B,
                                               u16* __restrict__ preq,
                                               u16* __restrict__ prek,
                                               u16* __restrict__ vT,
                                               float* __restrict__ Cf) {
  __shared__ u16 As[2][16384];
  __shared__ u16 Bs[2][16384];
  const int tid = threadIdx.x;
  const int wid = tid >> 6, lane = tid & 63;
  const int l16 = lane & 15, lq = lane >> 4;
  const int wm = wid >> 2, wn = wid & 3;
  const int bm = blockIdx.x & 31;            // M = 8192 -> 32 tiles
  const int bn = blockIdx.x >> 5;
  const int m0 = bm << 8, n0 = bn << 8;
  const int sw = l16 & 7;

  const int row0 = tid >> 3;                 // 0..63
  const int ch0 = ((tid & 7) ^ (row0 & 7)) << 3;
  const u16* Abase = A + (size_t)(m0 + row0) * K + ch0;
  const u16* Bbase = B + (size_t)(n0 + row0) * K + ch0;
  const int dst0 = tid * 8;

  const int CA = (wm * 128 + l16) * 64;
  const int CB = (wn * 64 + l16) * 64;
  const int ch_0 = ((0 | lq) ^ sw) << 3;
  const int ch_1 = ((4 | lq) ^ sw) << 3;

  f32x4 acc[8][4] = {};
  bf16x8 aF[4][2], bF[2][2][2];

#define STG(Larr, bufp, hh, gbase, kt) do {                                     \
    const u16* g_ = (gbase) + (size_t)(hh) * 128 * K + (size_t)(kt) * 64;       \
    gld_lds16(g_, &Larr[bufp][(hh) * 8192 + dst0]);                             \
    gld_lds16(g_ + (size_t)64 * K, &Larr[bufp][(hh) * 8192 + dst0 + 4096]);     \
  } while (0)

#define RDA(bufp, a) do {                                                       \
    _Pragma("unroll") for (int mb = 0; mb < 4; mb++) {                          \
      aF[mb][0] = *(const bf16x8*)(&As[bufp][CA + (a) * 4096 + mb * 1024 + ch_0]); \
      aF[mb][1] = *(const bf16x8*)(&As[bufp][CA + (a) * 4096 + mb * 1024 + ch_1]); \
    } } while (0)

#define RDB(bufp, b) do {                                                       \
    _Pragma("unroll") for (int nb = 0; nb < 2; nb++) {                          \
      bF[b][nb][0] = *(const bf16x8*)(&Bs[bufp][CB + (b) * 2048 + nb * 1024 + ch_0]); \
      bF[b][nb][1] = *(const bf16x8*)(&Bs[bufp][CB + (b) * 2048 + nb * 1024 + ch_1]); \
    } } while (0)

#define MFQ(a, b) do {                                                          \
    __builtin_amdgcn_s_setprio(1);                                              \
    _Pragma("unroll") for (int mb = 0; mb < 4; mb++)                            \
    _Pragma("unroll") for (int nb = 0; nb < 2; nb++)                            \
    _Pragma("unroll") for (int kk = 0; kk < 2; kk++)                            \
      acc[(a) * 4 + mb][(b) * 2 + nb] = __builtin_amdgcn_mfma_f32_16x16x32_bf16( \
          aF[mb][kk], bF[b][nb][kk], acc[(a) * 4 + mb][(b) * 2 + nb], 0, 0, 0); \
    __builtin_amdgcn_s_setprio(0); } while (0)

  STG(Bs, 0, 0, Bbase, 0);
  STG(As, 0, 0, Abase, 0);
  STG(Bs, 0, 1, Bbase, 0);
  STG(As, 0, 1, Abase, 0);
  STG(Bs, 1, 0, Bbase, 1);
  STG(As, 1, 0, Abase, 1);
  VMC4();
  BARR();

  const int NIT = K / 128;
  for (int i = 0; i < NIT; i++) {
    const bool lastI = (i == NIT - 1);
    const int k1 = 2 * i + 1, k2 = 2 * i + 2, k3 = 2 * i + 3;
    RDA(0, 0); RDB(0, 0);
    STG(Bs, 1, 1, Bbase, k1);
    MFQ(0, 0); VMC8(); BARR();
    RDB(0, 1);
    STG(As, 1, 1, Abase, k1);
    MFQ(0, 1); VMC8(); BARR();
    RDA(0, 1);
    if (!lastI) STG(Bs, 0, 0, Bbase, k2);
    MFQ(1, 0);
    if (!lastI) VMC8(); else VMC6();
    BARR();
    if (!lastI) STG(As, 0, 0, Abase, k2);
    MFQ(1, 1);
    if (!lastI) VMC8(); else VMC4();
    BARR();
    RDA(1, 0); RDB(1, 0);
    if (!lastI) STG(Bs, 0, 1, Bbase, k2);
    MFQ(0, 0);
    if (!lastI) VMC8(); else VMC2();
    BARR();
    RDB(1, 1);
    if (!lastI) STG(As, 0, 1, Abase, k2);
    MFQ(0, 1);
    if (!lastI) VMC8(); else VMC0();
    BARR();
    RDA(1, 1);
    if (!lastI) STG(Bs, 1, 0, Bbase, k3);
    MFQ(1, 0);
    if (!lastI) VMC8();
    BARR();
    if (!lastI) {
      STG(As, 1, 0, Abase, k3);
      MFQ(1, 1); VMC8(); BARR();
    } else {
      MFQ(1, 1);
    }
  }
#undef STG
#undef RDA
#undef RDB
#undef MFQ

  if (MODE == 0) {
    if (n0 < 2560) {
      u16* dst; int c0;
      if (n0 < 1280) { dst = preq; c0 = n0; }
      else           { dst = prek; c0 = n0 - 1280; }
#pragma unroll
      for (int mi = 0; mi < 8; mi++)
#pragma unroll
        for (int j = 0; j < 4; j++) {
          const size_t rowo = (size_t)(m0 + wm * 128 + mi * 16 + lq * 4 + j) * E_DIM;
#pragma unroll
          for (int ni = 0; ni < 4; ni++)
            dst[rowo + c0 + wn * 64 + ni * 16 + l16] = f2bf(acc[mi][ni][j]);
        }
    } else {
      const int c0 = n0 - 2560;
#pragma unroll
      for (int mi = 0; mi < 8; mi++)
#pragma unroll
        for (int ni = 0; ni < 4; ni++) {
          ushort4 pkt;
          pkt.x = f2bf(acc[mi][ni][0]); pkt.y = f2bf(acc[mi][ni][1]);
          pkt.z = f2bf(acc[mi][ni][2]); pkt.w = f2bf(acc[mi][ni][3]);
          const size_t off = (size_t)(c0 + wn * 64 + ni * 16 + l16) * T_TOK +
                             (m0 + wm * 128 + mi * 16 + lq * 4);
          *(ushort4*)(vT + off) = pkt;
        }
    }
  } else {
#pragma unroll
    for (int mi = 0; mi < 8; mi++)
#pragma unroll
      for (int j = 0; j < 4; j++) {
        const size_t rowo = (size_t)(m0 + wm * 128 + mi * 16 + lq * 4 + j) * E_DIM;
#pragma unroll
        for (int ni = 0; ni < 4; ni++)
          Cf[rowo + n0 + wn * 64 + ni * 16 + l16] = acc[mi][ni][j];
      }
  }
}

// ---------------- flash attention: swapped-QK 32x32, no-max exp2 softmax ----
__global__ __launch_bounds__(256) void attn_kernel(const u16* __restrict__ q,
                                                   const u16* __restrict__ k,
                                                   const u16* __restrict__ vT,
                                                   const int* __restrict__ cu,
                                                   u16* __restrict__ o) {
  const int bx = blockIdx.x;
  const int hb = bx % (NH * NSEQ);
  const int qt = bx / (NH * NSEQ);
  const int hh = hb % NH;
  const int b  = hb / NH;
  const int base = cu[b];
  const int nkt  = (cu[b + 1] - base) >> 6;
  const int tid  = threadIdx.x;
  const int wid  = tid >> 6, lane = tid & 63;
  const int l31  = lane & 31, hi = lane >> 5;

  __shared__ u16 Ks[2][64 * 64];
  __shared__ u16 Vs[2][64 * 64];

  const int qrow = base + qt * 128 + wid * 32 + l31;
  bf16x8 qf[4];
#pragma unroll
  for (int kk = 0; kk < 4; kk++)
    qf[kk] = *(const bf16x8*)(q + (size_t)qrow * E_DIM + hh * 64 + kk * 16 + hi * 8);

  f32x16 acc0 = {}, acc1 = {};
  float lrow = 0.f;

  const int r0 = tid >> 3;
  const int chs = tid & 7;
  const int cs0 = (chs ^ (r0 & 7)) << 3;
  const int r1 = r0 + 32;
  const int cs1 = (chs ^ (r1 & 7)) << 3;
  const u16* kg0 = k  + (size_t)(base + r0) * E_DIM + hh * 64 + cs0;
  const u16* kg1 = k  + (size_t)(base + r1) * E_DIM + hh * 64 + cs1;
  const u16* vg0 = vT + (size_t)(hh * 64 + r0) * T_TOK + base + cs0;
  const u16* vg1 = vT + (size_t)(hh * 64 + r1) * T_TOK + base + cs1;
  const int ldsoff = wid * 512;

  gld_lds16(kg0, &Ks[0][ldsoff]);
  gld_lds16(kg1, &Ks[0][2048 + ldsoff]);
  gld_lds16(vg0, &Vs[0][ldsoff]);
  gld_lds16(vg1, &Vs[0][2048 + ldsoff]);
  __syncthreads();

  int cur = 0;
  for (int kt = 0; kt < nkt; kt++) {
    if (kt + 1 < nkt) {
      const size_t ko = (size_t)(kt + 1) * 64 * E_DIM;
      const int vo = (kt + 1) * 64;
      u16* kd = Ks[cur ^ 1];
      u16* vd = Vs[cur ^ 1];
      gld_lds16(kg0 + ko, kd + ldsoff);
      gld_lds16(kg1 + ko, kd + 2048 + ldsoff);
      gld_lds16(vg0 + vo, vd + ldsoff);
      gld_lds16(vg1 + vo, vd + 2048 + ldsoff);
    }
    const u16* Kc = Ks[cur];
    const u16* Vc = Vs[cur];

    f32x16 S0 = {}, S1 = {};
#pragma unroll
    for (int kk = 0; kk < 4; kk++) {
      const int c0 = (((kk << 1) | hi) ^ (l31 & 7)) << 3;
      const bf16x8 kf0 = *(const bf16x8*)(Kc + l31 * 64 + c0);
      const bf16x8 kf1 = *(const bf16x8*)(Kc + (32 + l31) * 64 + c0);
      S0 = __builtin_amdgcn_mfma_f32_32x32x16_bf16(kf0, qf[kk], S0, 0, 0, 0);
      S1 = __builtin_amdgcn_mfma_f32_32x32x16_bf16(kf1, qf[kk], S1, 0, 0, 0);
    }

    float rs0 = 0.f, rs1 = 0.f, rs2 = 0.f, rs3 = 0.f;
#pragma unroll
    for (int r = 0; r < 16; r += 4) {
      S0[r + 0] = exp2f(S0[r + 0]); S0[r + 1] = exp2f(S0[r + 1]);
      S0[r + 2] = exp2f(S0[r + 2]); S0[r + 3] = exp2f(S0[r + 3]);
      rs0 += S0[r + 0]; rs1 += S0[r + 1]; rs2 += S0[r + 2]; rs3 += S0[r + 3];
    }
#pragma unroll
    for (int r = 0; r < 16; r += 4) {
      S1[r + 0] = exp2f(S1[r + 0]); S1[r + 1] = exp2f(S1[r + 1]);
      S1[r + 2] = exp2f(S1[r + 2]); S1[r + 3] = exp2f(S1[r + 3]);
      rs0 += S1[r + 0]; rs1 += S1[r + 1]; rs2 += S1[r + 2]; rs3 += S1[r + 3];
    }
    float rs = (rs0 + rs1) + (rs2 + rs3);
    rs += __shfl_xor(rs, 32);
    lrow += rs;

    u32 pw[4][4];
#pragma unroll
    for (int ks = 0; ks < 4; ks++) {
      const int g = (ks & 1) << 3;
      u32 A0, A1, B0, B1;
      if (ks < 2) {
        A0 = cvtpk(S0[g + 0], S0[g + 1]); A1 = cvtpk(S0[g + 2], S0[g + 3]);
        B0 = cvtpk(S0[g + 4], S0[g + 5]); B1 = cvtpk(S0[g + 6], S0[g + 7]);
      } else {
        A0 = cvtpk(S1[g + 0], S1[g + 1]); A1 = cvtpk(S1[g + 2], S1[g + 3]);
        B0 = cvtpk(S1[g + 4], S1[g + 5]); B1 = cvtpk(S1[g + 6], S1[g + 7]);
      }
      asm("v_permlane32_swap_b32 %0, %1" : "+v"(A0), "+v"(B0));
      asm("v_permlane32_swap_b32 %0, %1" : "+v"(A1), "+v"(B1));
      pw[ks][0] = A0; pw[ks][1] = A1; pw[ks][2] = B0; pw[ks][3] = B1;
    }

#pragma unroll
    for (int ks = 0; ks < 4; ks++) {
      const bf16x8 pa = *(const bf16x8*)&pw[ks][0];
      const int c0 = (((ks << 1) | hi) ^ (l31 & 7)) << 3;
      const bf16x8 vf0 = *(const bf16x8*)(Vc + l31 * 64 + c0);
      const bf16x8 vf1 = *(const bf16x8*)(Vc + (32 + l31) * 64 + c0);
      acc0 = __builtin_amdgcn_mfma_f32_32x32x16_bf16(pa, vf0, acc0, 0, 0, 0);
      acc1 = __builtin_amdgcn_mfma_f32_32x32x16_bf16(pa, vf1, acc1, 0, 0, 0);
    }
    __syncthreads();
    cur ^= 1;
  }

  const float linv = 1.0f / lrow;
  const int tok0 = base + qt * 128 + wid * 32;
#pragma unroll
  for (int r = 0; r < 16; r++) {
    const int qr = (r & 3) + 8 * (r >> 2) + 4 * hi;
    const float ls = __shfl(linv, qr);
    const size_t ro = (size_t)(tok0 + qr) * E_DIM + hh * 64 + l31;
    o[ro]      = f2bf(acc0[r] * ls);
    o[ro + 32] = f2bf(acc1[r] * ls);
  }
}

// ---------------- launch ----------------
extern "C" void kernel_launch(void* const* d_in, const int* in_sizes, int n_in,
                              void* d_out, int out_size, void* d_ws, size_t ws_size,
                              hipStream_t stream) {
  const float* x      = (const float*)d_in[0];
  const int*   cu     = (const int*)d_in[1];
  const float* norm_w = (const float*)d_in[3];
  const float* norm_b = (const float*)d_in[4];
  const float* Wq     = (const float*)d_in[5];
  const float* Wk     = (const float*)d_in[6];
  const float* Wv     = (const float*)d_in[7];
  const float* Wo     = (const float*)d_in[8];
  const float* lnq    = (const float*)d_in[9];
  const float* lnk    = (const float*)d_in[10];
  float* out = (float*)d_out;

  const size_t EE2 = (size_t)E_DIM * E_DIM * 2;
  const size_t TE2 = (size_t)T_TOK * E_DIM * 2;
  char* p = (char*)d_ws;
  u16* wqkv = (u16*)p; p += 3 * EE2;
  u16* wo_b = (u16*)p; p += EE2;
  u16* h_b  = (u16*)p; p += TE2;   // later: attention output
  u16* preq = (u16*)p; p += TE2;
  u16* prek = (u16*)p; p += TE2;
  u16* vT_b = (u16*)p; p += TE2;
  float2* tab = (float2*)p; p += 1024 * 32 * sizeof(float2);

  prep_ln_kernel<<<PREP_GRID, 320, 0, stream>>>(Wq, Wk, Wv, Wo, wqkv, wo_b, tab,
                                                x, norm_w, norm_b, h_b);

  // QKV: M=8192, N=3840 -> 32 x 15 = 480 blocks
  gemm256<0, E_DIM><<<480, 512, 0, stream>>>(h_b, wqkv, preq, prek, vT_b, nullptr);

  // fused q+k LN+RoPE (q pre-scaled by 0.125*log2e)
  ln_rope2_kernel<<<2 * T_TOK, 320, 0, stream>>>(preq, prek, lnq, lnk, cu, tab, preq, prek);

  attn_kernel<<<8 * NH * NSEQ, 256, 0, stream>>>(preq, prek, vT_b, cu, h_b);

  // OUT: M=8192, N=1280 -> 32 x 5 = 160 blocks
  gemm256<1, E_DIM><<<160, 512, 0, stream>>>(h_b, wo_b, nullptr, nullptr, nullptr, out);
}

// Round 16
// 246.643 us; speedup vs baseline: 1.2142x; 1.0138x over previous
//
#include <hip/hip_runtime.h>
#include <hip/hip_bf16.h>
#include <math.h>

#define NH 20
#define HD 64
#define E_DIM 1280
#define T_TOK 8192
#define NSEQ 8
#define N4 (E_DIM * E_DIM / 4)

#define SCALE_LOG2 0.1803368801111204f   // 0.125 * log2(e)

typedef unsigned short u16;
typedef unsigned int u32;
typedef __attribute__((ext_vector_type(8))) short bf16x8;
typedef __attribute__((ext_vector_type(4))) float f32x4;
typedef __attribute__((ext_vector_type(16))) float f32x16;

__device__ __forceinline__ float bf2f(u16 h) {
  union { float f; unsigned u; } c; c.u = ((unsigned)h) << 16; return c.f;
}
__device__ __forceinline__ u16 f2bf(float f) {
  union { float f; unsigned u; } c; c.f = f;
  unsigned u = c.u;
  return (u16)((u + 0x7fffu + ((u >> 16) & 1u)) >> 16);
}
__device__ __forceinline__ u32 cvtpk(float lo, float hi) {
  u32 r;
  asm("v_cvt_pk_bf16_f32 %0, %1, %2" : "=v"(r) : "v"(lo), "v"(hi));
  return r;
}

__device__ __forceinline__ void gld_lds16(const void* g, void* l) {
  __builtin_amdgcn_global_load_lds((const __attribute__((address_space(1))) void*)g,
                                   (__attribute__((address_space(3))) void*)l,
                                   16, 0, 0);
}

#define BARR() __builtin_amdgcn_s_barrier()
#define VMC8() asm volatile("s_waitcnt vmcnt(8)" ::: "memory")
#define VMC6() asm volatile("s_waitcnt vmcnt(6)" ::: "memory")
#define VMC4() asm volatile("s_waitcnt vmcnt(4)" ::: "memory")
#define VMC2() asm volatile("s_waitcnt vmcnt(2)" ::: "memory")
#define VMC0() asm volatile("s_waitcnt vmcnt(0)" ::: "memory")

// -------- fused: weights fp32->bf16 + RoPE table + pre-norm LN(x), 1 launch.
#define CVT_B 5120
#define TAB_B 103
#define PREP_GRID (CVT_B + TAB_B + T_TOK)
__global__ __launch_bounds__(320) void prep_ln_kernel(
    const float* __restrict__ Wq, const float* __restrict__ Wk,
    const float* __restrict__ Wv, const float* __restrict__ Wo,
    u16* __restrict__ wqkv, u16* __restrict__ wo, float2* __restrict__ tab,
    const float* __restrict__ x, const float* __restrict__ nw,
    const float* __restrict__ nb, u16* __restrict__ h) {
  const int bx = blockIdx.x;
  const int tid = threadIdx.x;
  __shared__ float ss[5], ss2[5];
  if (bx < CVT_B) {
    int i = bx * 320 + tid;                  // < 4*N4 exactly
    int r = i / N4;
    int l = i - r * N4;
    const float* src = (r == 0) ? Wq : (r == 1) ? Wk : (r == 2) ? Wv : Wo;
    float4 v = ((const float4*)src)[l];
    ushort4 ov;
    ov.x = f2bf(v.x); ov.y = f2bf(v.y); ov.z = f2bf(v.z); ov.w = f2bf(v.w);
    if (r < 3) ((ushort4*)wqkv)[(size_t)r * N4 + l] = ov;
    else       ((ushort4*)wo)[l] = ov;
  } else if (bx < CVT_B + TAB_B) {
    int i = (bx - CVT_B) * 320 + tid;        // 0..32767
    if (i >= 1024 * 32) return;
    int pos = i >> 5, dm = i & 31;
    float freq = exp2f(-(float)dm * (13.287712379549449f / 32.0f));
    float f = (float)pos * freq;
    tab[i] = make_float2(cosf(f), sinf(f));
  } else {
    const int row = bx - (CVT_B + TAB_B);    // 0..8191
    const float4 xv = ((const float4*)(x + (size_t)row * E_DIM))[tid];
    float s  = xv.x + xv.y + xv.z + xv.w;
    float s2 = xv.x*xv.x + xv.y*xv.y + xv.z*xv.z + xv.w*xv.w;
#pragma unroll
    for (int m = 1; m < 64; m <<= 1) { s += __shfl_xor(s, m); s2 += __shfl_xor(s2, m); }
    if ((tid & 63) == 0) { ss[tid >> 6] = s; ss2[tid >> 6] = s2; }
    __syncthreads();
    s  = ss[0] + ss[1] + ss[2] + ss[3] + ss[4];
    s2 = ss2[0] + ss2[1] + ss2[2] + ss2[3] + ss2[4];
    const float mean = s * (1.0f / E_DIM);
    const float var  = s2 * (1.0f / E_DIM) - mean * mean;
    const float rstd = rsqrtf(var + 1e-5f);
    const float4 wv = ((const float4*)nw)[tid];
    const float4 bv = ((const float4*)nb)[tid];
    ushort4 o;
    o.x = f2bf((xv.x - mean) * rstd * wv.x + bv.x);
    o.y = f2bf((xv.y - mean) * rstd * wv.y + bv.y);
    o.z = f2bf((xv.z - mean) * rstd * wv.z + bv.z);
    o.w = f2bf((xv.w - mean) * rstd * wv.w + bv.w);
    ((ushort4*)(h + (size_t)row * E_DIM))[tid] = o;
  }
}

// ------- fused LN (no bias) + RoPE for q and k in one launch -------------
__global__ __launch_bounds__(320) void ln_rope2_kernel(const u16* __restrict__ preq,
                                                       const u16* __restrict__ prek,
                                                       const float* __restrict__ wq,
                                                       const float* __restrict__ wk,
                                                       const int* __restrict__ cu,
                                                       const float2* __restrict__ tab,
                                                       u16* __restrict__ outq,
                                                       u16* __restrict__ outk) {
  const int sel = blockIdx.x >> 13;
  const int row = blockIdx.x & (T_TOK - 1);
  const u16* pre = sel ? prek : preq;
  const float* w = sel ? wk : wq;
  u16* outp = sel ? outk : outq;
  const float oscale = sel ? 1.0f : SCALE_LOG2;
  const int tid = threadIdx.x;
  __shared__ float y[E_DIM];
  const ushort4 qv = ((const ushort4*)(pre + (size_t)row * E_DIM))[tid];
  float v0 = bf2f(qv.x), v1 = bf2f(qv.y), v2 = bf2f(qv.z), v3 = bf2f(qv.w);
  float s  = v0 + v1 + v2 + v3;
  float s2 = v0*v0 + v1*v1 + v2*v2 + v3*v3;
#pragma unroll
  for (int m = 1; m < 64; m <<= 1) { s += __shfl_xor(s, m); s2 += __shfl_xor(s2, m); }
  __shared__ float ss[5], ss2[5];
  if ((tid & 63) == 0) { ss[tid >> 6] = s; ss2[tid >> 6] = s2; }
  __syncthreads();
  s  = ss[0] + ss[1] + ss[2] + ss[3] + ss[4];
  s2 = ss2[0] + ss2[1] + ss2[2] + ss2[3] + ss2[4];
  const float mean = s * (1.0f / E_DIM);
  const float var  = s2 * (1.0f / E_DIM) - mean * mean;
  const float rstd = rsqrtf(var + 1e-5f);
  const int e0 = tid * 4;
  float4 wv = ((const float4*)w)[tid];
  wv.x *= oscale; wv.y *= oscale; wv.z *= oscale; wv.w *= oscale;
  y[e0 + 0] = (v0 - mean) * rstd * wv.x;
  y[e0 + 1] = (v1 - mean) * rstd * wv.y;
  y[e0 + 2] = (v2 - mean) * rstd * wv.z;
  y[e0 + 3] = (v3 - mean) * rstd * wv.w;
  __syncthreads();
  int seg = 0;
#pragma unroll
  for (int bb = 1; bb < NSEQ + 1; bb++) if (cu[bb] <= row) seg = bb;
  const int pos = row - cu[seg];
  const int d0 = e0 & 63;
  const int hbase = e0 - d0;
  const float4* tp = (const float4*)(tab + pos * 32 + (d0 & 31));
  const float4 t0 = tp[0], t1 = tp[1];
  const float cs_[4] = {t0.x, t0.z, t1.x, t1.z};
  const float sn_[4] = {t0.y, t0.w, t1.y, t1.w};
  const bool lo = (d0 < 32);
  ushort4 o;
#pragma unroll
  for (int i = 0; i < 4; i++) {
    const int d = d0 + i;
    float r;
    if (lo) r = y[hbase + d] * cs_[i] - y[hbase + d + 32] * sn_[i];
    else    r = y[hbase + d] * cs_[i] + y[hbase + d - 32] * sn_[i];
    ((u16*)&o)[i] = f2bf(r);
  }
  ((ushort4*)(outp + (size_t)row * E_DIM))[tid] = o;
}

// ---------------- 256x256 8-phase GEMM (R14 schedule, measured-best) ------
// QKV only now (grid 480 = 2 nearly-full rounds).
template <int MODE, int K>
__global__ __launch_bounds__(512) void gemm256(const u16* __restrict__ A,
                                               const u16* __restrict__ B,
                                               u16* __restrict__ preq,
                                               u16* __restrict__ prek,
                                               u16* __restrict__ vT,
                                               float* __restrict__ Cf) {
  __shared__ u16 As[2][16384];
  __shared__ u16 Bs[2][16384];
  const int tid = threadIdx.x;
  const int wid = tid >> 6, lane = tid & 63;
  const int l16 = lane & 15, lq = lane >> 4;
  const int wm = wid >> 2, wn = wid & 3;
  const int bm = blockIdx.x & 31;            // M = 8192 -> 32 tiles
  const int bn = blockIdx.x >> 5;
  const int m0 = bm << 8, n0 = bn << 8;
  const int sw = l16 & 7;

  const int row0 = tid >> 3;                 // 0..63
  const int ch0 = ((tid & 7) ^ (row0 & 7)) << 3;
  const u16* Abase = A + (size_t)(m0 + row0) * K + ch0;
  const u16* Bbase = B + (size_t)(n0 + row0) * K + ch0;
  const int dst0 = tid * 8;

  const int CA = (wm * 128 + l16) * 64;
  const int CB = (wn * 64 + l16) * 64;
  const int ch_0 = ((0 | lq) ^ sw) << 3;
  const int ch_1 = ((4 | lq) ^ sw) << 3;

  f32x4 acc[8][4] = {};
  bf16x8 aF[4][2], bF[2][2][2];

#define STG(Larr, bufp, hh, gbase, kt) do {                                     \
    const u16* g_ = (gbase) + (size_t)(hh) * 128 * K + (size_t)(kt) * 64;       \
    gld_lds16(g_, &Larr[bufp][(hh) * 8192 + dst0]);                             \
    gld_lds16(g_ + (size_t)64 * K, &Larr[bufp][(hh) * 8192 + dst0 + 4096]);     \
  } while (0)

#define RDA(bufp, a) do {                                                       \
    _Pragma("unroll") for (int mb = 0; mb < 4; mb++) {                          \
      aF[mb][0] = *(const bf16x8*)(&As[bufp][CA + (a) * 4096 + mb * 1024 + ch_0]); \
      aF[mb][1] = *(const bf16x8*)(&As[bufp][CA + (a) * 4096 + mb * 1024 + ch_1]); \
    } } while (0)

#define RDB(bufp, b) do {                                                       \
    _Pragma("unroll") for (int nb = 0; nb < 2; nb++) {                          \
      bF[b][nb][0] = *(const bf16x8*)(&Bs[bufp][CB + (b) * 2048 + nb * 1024 + ch_0]); \
      bF[b][nb][1] = *(const bf16x8*)(&Bs[bufp][CB + (b) * 2048 + nb * 1024 + ch_1]); \
    } } while (0)

#define MFQ(a, b) do {                                                          \
    __builtin_amdgcn_s_setprio(1);                                              \
    _Pragma("unroll") for (int mb = 0; mb < 4; mb++)                            \
    _Pragma("unroll") for (int nb = 0; nb < 2; nb++)                            \
    _Pragma("unroll") for (int kk = 0; kk < 2; kk++)                            \
      acc[(a) * 4 + mb][(b) * 2 + nb] = __builtin_amdgcn_mfma_f32_16x16x32_bf16( \
          aF[mb][kk], bF[b][nb][kk], acc[(a) * 4 + mb][(b) * 2 + nb], 0, 0, 0); \
    __builtin_amdgcn_s_setprio(0); } while (0)

  STG(Bs, 0, 0, Bbase, 0);
  STG(As, 0, 0, Abase, 0);
  STG(Bs, 0, 1, Bbase, 0);
  STG(As, 0, 1, Abase, 0);
  STG(Bs, 1, 0, Bbase, 1);
  STG(As, 1, 0, Abase, 1);
  VMC4();
  BARR();

  const int NIT = K / 128;
  for (int i = 0; i < NIT; i++) {
    const bool lastI = (i == NIT - 1);
    const int k1 = 2 * i + 1, k2 = 2 * i + 2, k3 = 2 * i + 3;
    RDA(0, 0); RDB(0, 0);
    STG(Bs, 1, 1, Bbase, k1);
    MFQ(0, 0); VMC8(); BARR();
    RDB(0, 1);
    STG(As, 1, 1, Abase, k1);
    MFQ(0, 1); VMC8(); BARR();
    RDA(0, 1);
    if (!lastI) STG(Bs, 0, 0, Bbase, k2);
    MFQ(1, 0);
    if (!lastI) VMC8(); else VMC6();
    BARR();
    if (!lastI) STG(As, 0, 0, Abase, k2);
    MFQ(1, 1);
    if (!lastI) VMC8(); else VMC4();
    BARR();
    RDA(1, 0); RDB(1, 0);
    if (!lastI) STG(Bs, 0, 1, Bbase, k2);
    MFQ(0, 0);
    if (!lastI) VMC8(); else VMC2();
    BARR();
    RDB(1, 1);
    if (!lastI) STG(As, 0, 1, Abase, k2);
    MFQ(0, 1);
    if (!lastI) VMC8(); else VMC0();
    BARR();
    RDA(1, 1);
    if (!lastI) STG(Bs, 1, 0, Bbase, k3);
    MFQ(1, 0);
    if (!lastI) VMC8();
    BARR();
    if (!lastI) {
      STG(As, 1, 0, Abase, k3);
      MFQ(1, 1); VMC8(); BARR();
    } else {
      MFQ(1, 1);
    }
  }
#undef STG
#undef RDA
#undef RDB
#undef MFQ

  if (MODE == 0) {
    if (n0 < 2560) {
      u16* dst; int c0;
      if (n0 < 1280) { dst = preq; c0 = n0; }
      else           { dst = prek; c0 = n0 - 1280; }
#pragma unroll
      for (int mi = 0; mi < 8; mi++)
#pragma unroll
        for (int j = 0; j < 4; j++) {
          const size_t rowo = (size_t)(m0 + wm * 128 + mi * 16 + lq * 4 + j) * E_DIM;
#pragma unroll
          for (int ni = 0; ni < 4; ni++)
            dst[rowo + c0 + wn * 64 + ni * 16 + l16] = f2bf(acc[mi][ni][j]);
        }
    } else {
      const int c0 = n0 - 2560;
#pragma unroll
      for (int mi = 0; mi < 8; mi++)
#pragma unroll
        for (int ni = 0; ni < 4; ni++) {
          ushort4 pkt;
          pkt.x = f2bf(acc[mi][ni][0]); pkt.y = f2bf(acc[mi][ni][1]);
          pkt.z = f2bf(acc[mi][ni][2]); pkt.w = f2bf(acc[mi][ni][3]);
          const size_t off = (size_t)(c0 + wn * 64 + ni * 16 + l16) * T_TOK +
                             (m0 + wm * 128 + mi * 16 + lq * 4);
          *(ushort4*)(vT + off) = pkt;
        }
    }
  } else {
#pragma unroll
    for (int mi = 0; mi < 8; mi++)
#pragma unroll
      for (int j = 0; j < 4; j++) {
        const size_t rowo = (size_t)(m0 + wm * 128 + mi * 16 + lq * 4 + j) * E_DIM;
#pragma unroll
        for (int ni = 0; ni < 4; ni++)
          Cf[rowo + n0 + wn * 64 + ni * 16 + l16] = acc[mi][ni][j];
      }
  }
}

// ------- OUT GEMM: 128x128 single-buffer + T2 swizzle (R5-verified) -------
// 640 blocks (64 M x 10 N), 32KB LDS -> ~4 blocks/CU, full-chip balance
// (vs 160 blocks of 256^2 = 62.5% CU utilization).
__global__ __launch_bounds__(256) void gemm_out128(const u16* __restrict__ A,
                                                   const u16* __restrict__ B,
                                                   float* __restrict__ C) {
  __shared__ u16 As[128 * 64];
  __shared__ u16 Bs[128 * 64];
  const int K = E_DIM, N = E_DIM;
  const int tid = threadIdx.x;
  const int wid = tid >> 6;
  const int lane = tid & 63;
  const int l16 = lane & 15, lq = lane >> 4;
  const int bm = blockIdx.x & 63;
  const int bn = blockIdx.x >> 6;
  const int m0 = bm << 7, n0 = bn << 7;
  const int wr = (wid >> 1) << 6;
  const int wc = (wid & 1) << 6;

  f32x4 acc[4][4] = {};
  const int rbase = tid >> 3;
  const int csw = (((tid & 7) ^ ((tid >> 3) & 7)) << 3);
  const int sw = l16 & 7;
  const int ldst = (wid << 6) * 8;

  for (int k0 = 0; k0 < K; k0 += 64) {
#pragma unroll
    for (int j = 0; j < 4; j++) {
      const int row = j * 32 + rbase;
      gld_lds16(A + (size_t)(m0 + row) * K + k0 + csw, &As[(size_t)(j * 2048) + ldst]);
      gld_lds16(B + (size_t)(n0 + row) * K + k0 + csw, &Bs[(size_t)(j * 2048) + ldst]);
    }
    __syncthreads();
#pragma unroll
    for (int kk = 0; kk < 2; kk++) {
      bf16x8 af[4], bfr[4];
#pragma unroll
      for (int mi = 0; mi < 4; mi++)
        af[mi] = *(const bf16x8*)(&As[(wr + mi * 16 + l16) * 64 + ((((kk << 2) | lq) ^ sw) << 3)]);
#pragma unroll
      for (int ni = 0; ni < 4; ni++)
        bfr[ni] = *(const bf16x8*)(&Bs[(wc + ni * 16 + l16) * 64 + ((((kk << 2) | lq) ^ sw) << 3)]);
#pragma unroll
      for (int mi = 0; mi < 4; mi++)
#pragma unroll
        for (int ni = 0; ni < 4; ni++)
          acc[mi][ni] = __builtin_amdgcn_mfma_f32_16x16x32_bf16(af[mi], bfr[ni], acc[mi][ni], 0, 0, 0);
    }
    __syncthreads();
  }

#pragma unroll
  for (int mi = 0; mi < 4; mi++)
#pragma unroll
    for (int j = 0; j < 4; j++) {
      const size_t rowo = (size_t)(m0 + wr + mi * 16 + lq * 4 + j) * N;
#pragma unroll
      for (int ni = 0; ni < 4; ni++)
        C[rowo + n0 + wc + ni * 16 + l16] = acc[mi][ni][j];
    }
}

// ---------------- flash attention: swapped-QK 32x32, no-max exp2 softmax ----
__global__ __launch_bounds__(256) void attn_kernel(const u16* __restrict__ q,
                                                   const u16* __restrict__ k,
                                                   const u16* __restrict__ vT,
                                                   const int* __restrict__ cu,
                                                   u16* __restrict__ o) {
  const int bx = blockIdx.x;
  const int hb = bx % (NH * NSEQ);
  const int qt = bx / (NH * NSEQ);
  const int hh = hb % NH;
  const int b  = hb / NH;
  const int base = cu[b];
  const int nkt  = (cu[b + 1] - base) >> 6;
  const int tid  = threadIdx.x;
  const int wid  = tid >> 6, lane = tid & 63;
  const int l31  = lane & 31, hi = lane >> 5;

  __shared__ u16 Ks[2][64 * 64];
  __shared__ u16 Vs[2][64 * 64];

  const int qrow = base + qt * 128 + wid * 32 + l31;
  bf16x8 qf[4];
#pragma unroll
  for (int kk = 0; kk < 4; kk++)
    qf[kk] = *(const bf16x8*)(q + (size_t)qrow * E_DIM + hh * 64 + kk * 16 + hi * 8);

  f32x16 acc0 = {}, acc1 = {};
  float lrow = 0.f;

  const int r0 = tid >> 3;
  const int chs = tid & 7;
  const int cs0 = (chs ^ (r0 & 7)) << 3;
  const int r1 = r0 + 32;
  const int cs1 = (chs ^ (r1 & 7)) << 3;
  const u16* kg0 = k  + (size_t)(base + r0) * E_DIM + hh * 64 + cs0;
  const u16* kg1 = k  + (size_t)(base + r1) * E_DIM + hh * 64 + cs1;
  const u16* vg0 = vT + (size_t)(hh * 64 + r0) * T_TOK + base + cs0;
  const u16* vg1 = vT + (size_t)(hh * 64 + r1) * T_TOK + base + cs1;
  const int ldsoff = wid * 512;

  gld_lds16(kg0, &Ks[0][ldsoff]);
  gld_lds16(kg1, &Ks[0][2048 + ldsoff]);
  gld_lds16(vg0, &Vs[0][ldsoff]);
  gld_lds16(vg1, &Vs[0][2048 + ldsoff]);
  __syncthreads();

  int cur = 0;
  for (int kt = 0; kt < nkt; kt++) {
    if (kt + 1 < nkt) {
      const size_t ko = (size_t)(kt + 1) * 64 * E_DIM;
      const int vo = (kt + 1) * 64;
      u16* kd = Ks[cur ^ 1];
      u16* vd = Vs[cur ^ 1];
      gld_lds16(kg0 + ko, kd + ldsoff);
      gld_lds16(kg1 + ko, kd + 2048 + ldsoff);
      gld_lds16(vg0 + vo, vd + ldsoff);
      gld_lds16(vg1 + vo, vd + 2048 + ldsoff);
    }
    const u16* Kc = Ks[cur];
    const u16* Vc = Vs[cur];

    f32x16 S0 = {}, S1 = {};
#pragma unroll
    for (int kk = 0; kk < 4; kk++) {
      const int c0 = (((kk << 1) | hi) ^ (l31 & 7)) << 3;
      const bf16x8 kf0 = *(const bf16x8*)(Kc + l31 * 64 + c0);
      const bf16x8 kf1 = *(const bf16x8*)(Kc + (32 + l31) * 64 + c0);
      S0 = __builtin_amdgcn_mfma_f32_32x32x16_bf16(kf0, qf[kk], S0, 0, 0, 0);
      S1 = __builtin_amdgcn_mfma_f32_32x32x16_bf16(kf1, qf[kk], S1, 0, 0, 0);
    }

    float rs0 = 0.f, rs1 = 0.f, rs2 = 0.f, rs3 = 0.f;
#pragma unroll
    for (int r = 0; r < 16; r += 4) {
      S0[r + 0] = exp2f(S0[r + 0]); S0[r + 1] = exp2f(S0[r + 1]);
      S0[r + 2] = exp2f(S0[r + 2]); S0[r + 3] = exp2f(S0[r + 3]);
      rs0 += S0[r + 0]; rs1 += S0[r + 1]; rs2 += S0[r + 2]; rs3 += S0[r + 3];
    }
#pragma unroll
    for (int r = 0; r < 16; r += 4) {
      S1[r + 0] = exp2f(S1[r + 0]); S1[r + 1] = exp2f(S1[r + 1]);
      S1[r + 2] = exp2f(S1[r + 2]); S1[r + 3] = exp2f(S1[r + 3]);
      rs0 += S1[r + 0]; rs1 += S1[r + 1]; rs2 += S1[r + 2]; rs3 += S1[r + 3];
    }
    float rs = (rs0 + rs1) + (rs2 + rs3);
    rs += __shfl_xor(rs, 32);
    lrow += rs;

    u32 pw[4][4];
#pragma unroll
    for (int ks = 0; ks < 4; ks++) {
      const int g = (ks & 1) << 3;
      u32 A0, A1, B0, B1;
      if (ks < 2) {
        A0 = cvtpk(S0[g + 0], S0[g + 1]); A1 = cvtpk(S0[g + 2], S0[g + 3]);
        B0 = cvtpk(S0[g + 4], S0[g + 5]); B1 = cvtpk(S0[g + 6], S0[g + 7]);
      } else {
        A0 = cvtpk(S1[g + 0], S1[g + 1]); A1 = cvtpk(S1[g + 2], S1[g + 3]);
        B0 = cvtpk(S1[g + 4], S1[g + 5]); B1 = cvtpk(S1[g + 6], S1[g + 7]);
      }
      asm("v_permlane32_swap_b32 %0, %1" : "+v"(A0), "+v"(B0));
      asm("v_permlane32_swap_b32 %0, %1" : "+v"(A1), "+v"(B1));
      pw[ks][0] = A0; pw[ks][1] = A1; pw[ks][2] = B0; pw[ks][3] = B1;
    }

#pragma unroll
    for (int ks = 0; ks < 4; ks++) {
      const bf16x8 pa = *(const bf16x8*)&pw[ks][0];
      const int c0 = (((ks << 1) | hi) ^ (l31 & 7)) << 3;
      const bf16x8 vf0 = *(const bf16x8*)(Vc + l31 * 64 + c0);
      const bf16x8 vf1 = *(const bf16x8*)(Vc + (32 + l31) * 64 + c0);
      acc0 = __builtin_amdgcn_mfma_f32_32x32x16_bf16(pa, vf0, acc0, 0, 0, 0);
      acc1 = __builtin_amdgcn_mfma_f32_32x32x16_bf16(pa, vf1, acc1, 0, 0, 0);
    }
    __syncthreads();
    cur ^= 1;
  }

  const float linv = 1.0f / lrow;
  const int tok0 = base + qt * 128 + wid * 32;
#pragma unroll
  for (int r = 0; r < 16; r++) {
    const int qr = (r & 3) + 8 * (r >> 2) + 4 * hi;
    const float ls = __shfl(linv, qr);
    const size_t ro = (size_t)(tok0 + qr) * E_DIM + hh * 64 + l31;
    o[ro]      = f2bf(acc0[r] * ls);
    o[ro + 32] = f2bf(acc1[r] * ls);
  }
}

// ---------------- launch ----------------
extern "C" void kernel_launch(void* const* d_in, const int* in_sizes, int n_in,
                              void* d_out, int out_size, void* d_ws, size_t ws_size,
                              hipStream_t stream) {
  const float* x      = (const float*)d_in[0];
  const int*   cu     = (const int*)d_in[1];
  const float* norm_w = (const float*)d_in[3];
  const float* norm_b = (const float*)d_in[4];
  const float* Wq     = (const float*)d_in[5];
  const float* Wk     = (const float*)d_in[6];
  const float* Wv     = (const float*)d_in[7];
  const float* Wo     = (const float*)d_in[8];
  const float* lnq    = (const float*)d_in[9];
  const float* lnk    = (const float*)d_in[10];
  float* out = (float*)d_out;

  const size_t EE2 = (size_t)E_DIM * E_DIM * 2;
  const size_t TE2 = (size_t)T_TOK * E_DIM * 2;
  char* p = (char*)d_ws;
  u16* wqkv = (u16*)p; p += 3 * EE2;
  u16* wo_b = (u16*)p; p += EE2;
  u16* h_b  = (u16*)p; p += TE2;   // later: attention output
  u16* preq = (u16*)p; p += TE2;
  u16* prek = (u16*)p; p += TE2;
  u16* vT_b = (u16*)p; p += TE2;
  float2* tab = (float2*)p; p += 1024 * 32 * sizeof(float2);

  prep_ln_kernel<<<PREP_GRID, 320, 0, stream>>>(Wq, Wk, Wv, Wo, wqkv, wo_b, tab,
                                                x, norm_w, norm_b, h_b);

  // QKV: M=8192, N=3840 -> 32 x 15 = 480 blocks (256^2 8-phase)
  gemm256<0, E_DIM><<<480, 512, 0, stream>>>(h_b, wqkv, preq, prek, vT_b, nullptr);

  // fused q+k LN+RoPE (q pre-scaled by 0.125*log2e)
  ln_rope2_kernel<<<2 * T_TOK, 320, 0, stream>>>(preq, prek, lnq, lnk, cu, tab, preq, prek);

  attn_kernel<<<8 * NH * NSEQ, 256, 0, stream>>>(preq, prek, vT_b, cu, h_b);

  // OUT: M=8192, N=1280 -> 64 x 10 = 640 blocks (128^2, full-chip balance)
  gemm_out128<<<640, 256, 0, stream>>>(h_b, wo_b, out);
}